// Round 1
// baseline (745.286 us; speedup 1.0000x reference)
//
#include <hip/hip_runtime.h>
#include <hip/hip_bf16.h>
#include <cstdint>

#define HD 128

// ---------------- CSR build ----------------

__global__ void k_zero(int* __restrict__ p, int n) {
    int i = blockIdx.x * 256 + threadIdx.x;
    if (i < n) p[i] = 0;
}

__global__ void k_count(const int* __restrict__ ei, int E, int* __restrict__ counts) {
    int e = blockIdx.x * 256 + threadIdx.x;
    if (e < E) atomicAdd(&counts[ei[E + e]], 1);   // dst = ei[1][e]
}

__global__ void k_scan1(const int* __restrict__ counts, int* __restrict__ offsets,
                        int* __restrict__ partials, int n) {
    __shared__ int sh[256];
    int i = blockIdx.x * 256 + threadIdx.x;
    int v = (i < n) ? counts[i] : 0;
    sh[threadIdx.x] = v;
    __syncthreads();
    for (int d = 1; d < 256; d <<= 1) {
        int t = (threadIdx.x >= (unsigned)d) ? sh[threadIdx.x - d] : 0;
        __syncthreads();
        sh[threadIdx.x] += t;
        __syncthreads();
    }
    if (i < n) offsets[i] = sh[threadIdx.x] - v;        // exclusive
    if (threadIdx.x == 255) partials[blockIdx.x] = sh[255];
}

__global__ void k_scan2(int* __restrict__ partials, int nb) {
    __shared__ int sh[256];
    int v = (threadIdx.x < (unsigned)nb) ? partials[threadIdx.x] : 0;
    sh[threadIdx.x] = v;
    __syncthreads();
    for (int d = 1; d < 256; d <<= 1) {
        int t = (threadIdx.x >= (unsigned)d) ? sh[threadIdx.x - d] : 0;
        __syncthreads();
        sh[threadIdx.x] += t;
        __syncthreads();
    }
    if (threadIdx.x < (unsigned)nb) partials[threadIdx.x] = sh[threadIdx.x] - v;  // exclusive
}

__global__ void k_scan3(int* __restrict__ offsets, int* __restrict__ cursor,
                        const int* __restrict__ partials, int n, int total) {
    int i = blockIdx.x * 256 + threadIdx.x;
    if (i < n) {
        int o = offsets[i] + partials[blockIdx.x];
        offsets[i] = o;
        cursor[i]  = o;
    }
    if (i == 0) offsets[n] = total;
}

__global__ void k_scatter(const int* __restrict__ ei, int E,
                          int* __restrict__ cursor, int* __restrict__ sorted_src) {
    int e = blockIdx.x * 256 + threadIdx.x;
    if (e < E) {
        int s = ei[e];
        int d = ei[E + e];
        int pos = atomicAdd(&cursor[d], 1);
        sorted_src[pos] = s;
    }
}

// ---------------- weight transpose (W[j][k] -> Wt[k][j]) ----------------

__global__ void k_transpose128(const float* __restrict__ w, float* __restrict__ wt) {
    int idx = blockIdx.x * 256 + threadIdx.x;   // 16384 elements, 64 blocks
    int j = idx >> 7, k = idx & 127;
    wt[k * HD + j] = w[idx];
}

// ---------------- mean aggregation (CSR gather) ----------------

__global__ __launch_bounds__(128) void k_aggr(const float* __restrict__ x,
                                              const int* __restrict__ offsets,
                                              const int* __restrict__ sorted_src,
                                              float* __restrict__ out) {
    int n = blockIdx.x;
    int t = threadIdx.x;          // 128 threads = 1 feature each
    int beg = offsets[n], end = offsets[n + 1];
    float acc = 0.f;
    __shared__ int sidx[128];
    for (int base = beg; base < end; base += 128) {
        int cnt = min(128, end - base);
        if (t < cnt) sidx[t] = sorted_src[base + t];
        __syncthreads();
        for (int e = 0; e < cnt; ++e)
            acc += x[(size_t)sidx[e] * HD + t];
        __syncthreads();
    }
    float deg = (float)(end - beg);
    out[(size_t)n * HD + t] = acc / fmaxf(deg, 1.0f);
}

// ---------------- fused (dual-)GEMM: out = relu(A@WlT + [B@WrT] + bias) ----------------

__device__ inline void fma4(float4& a, float s, float4 w) {
    a.x = fmaf(s, w.x, a.x);
    a.y = fmaf(s, w.y, a.y);
    a.z = fmaf(s, w.z, a.z);
    a.w = fmaf(s, w.w, a.w);
}

template <bool DUAL>
__global__ __launch_bounds__(256) void k_gemm(const float* __restrict__ A,
                                              const float* __restrict__ B,
                                              const float* __restrict__ WlT,
                                              const float* __restrict__ WrT,
                                              const float* __restrict__ bias,
                                              float* __restrict__ out, int nrows) {
    __shared__ float4 As[64 * 32];
    __shared__ float4 Bs[DUAL ? 64 * 32 : 1];
    int row0 = blockIdx.x * 64;

    for (int i = threadIdx.x; i < 64 * 32; i += 256) {
        int r = i >> 5;
        int row = row0 + r;
        float4 z = make_float4(0.f, 0.f, 0.f, 0.f);
        As[i] = (row < nrows) ? ((const float4*)A)[(size_t)row * 32 + (i & 31)] : z;
        if (DUAL)
            Bs[i] = (row < nrows) ? ((const float4*)B)[(size_t)row * 32 + (i & 31)] : z;
    }
    __syncthreads();

    int c  = threadIdx.x & 31;   // cols 4c..4c+3
    int rg = threadIdx.x >> 5;   // rows rg*8..rg*8+7
    float4 acc[8];
#pragma unroll
    for (int r = 0; r < 8; ++r) acc[r] = make_float4(0.f, 0.f, 0.f, 0.f);

    const float4* wl4 = (const float4*)WlT;
    const float4* wr4 = (const float4*)WrT;

#pragma unroll 4
    for (int k4 = 0; k4 < 32; ++k4) {
        float4 wl0 = wl4[(k4 * 4 + 0) * 32 + c];
        float4 wl1 = wl4[(k4 * 4 + 1) * 32 + c];
        float4 wl2 = wl4[(k4 * 4 + 2) * 32 + c];
        float4 wl3 = wl4[(k4 * 4 + 3) * 32 + c];
        float4 wr0, wr1, wr2, wr3;
        if (DUAL) {
            wr0 = wr4[(k4 * 4 + 0) * 32 + c];
            wr1 = wr4[(k4 * 4 + 1) * 32 + c];
            wr2 = wr4[(k4 * 4 + 2) * 32 + c];
            wr3 = wr4[(k4 * 4 + 3) * 32 + c];
        }
#pragma unroll
        for (int r = 0; r < 8; ++r) {
            float4 a = As[(rg * 8 + r) * 32 + k4];
            fma4(acc[r], a.x, wl0);
            fma4(acc[r], a.y, wl1);
            fma4(acc[r], a.z, wl2);
            fma4(acc[r], a.w, wl3);
            if (DUAL) {
                float4 b = Bs[(rg * 8 + r) * 32 + k4];
                fma4(acc[r], b.x, wr0);
                fma4(acc[r], b.y, wr1);
                fma4(acc[r], b.z, wr2);
                fma4(acc[r], b.w, wr3);
            }
        }
    }

    float4 b4 = ((const float4*)bias)[c];
#pragma unroll
    for (int r = 0; r < 8; ++r) {
        int row = row0 + rg * 8 + r;
        if (row < nrows) {
            float4 o;
            o.x = fmaxf(acc[r].x + b4.x, 0.f);
            o.y = fmaxf(acc[r].y + b4.y, 0.f);
            o.z = fmaxf(acc[r].z + b4.z, 0.f);
            o.w = fmaxf(acc[r].w + b4.w, 0.f);
            ((float4*)out)[(size_t)row * 32 + c] = o;
        }
    }
}

// ---------------- final: logits = h @ mw2.T + mb2 ----------------

__global__ void k_final(const float* __restrict__ h, const float* __restrict__ w,
                        const float* __restrict__ b, float* __restrict__ out, int n) {
    int i = blockIdx.x * 256 + threadIdx.x;
    if (i >= n) return;
    const float4* hp = (const float4*)(h + (size_t)i * HD);
    const float4* wp = (const float4*)w;   // uniform -> scalar loads
    float acc = 0.f;
#pragma unroll
    for (int k = 0; k < 32; ++k) {
        float4 hv = hp[k];
        float4 wv = wp[k];
        acc += hv.x * wv.x + hv.y * wv.y + hv.z * wv.z + hv.w * wv.w;
    }
    out[i] = acc + b[0];
}

// ---------------- launch ----------------

extern "C" void kernel_launch(void* const* d_in, const int* in_sizes, int n_in,
                              void* d_out, int out_size, void* d_ws, size_t ws_size,
                              hipStream_t stream) {
    const float* x   = (const float*)d_in[0];
    const int*   ei  = (const int*)d_in[1];   // [2,E] int32 (JAX x64 disabled)
    const float* w1l = (const float*)d_in[2];
    const float* b1l = (const float*)d_in[3];
    const float* w1r = (const float*)d_in[4];
    const float* w2l = (const float*)d_in[5];
    const float* b2l = (const float*)d_in[6];
    const float* w2r = (const float*)d_in[7];
    const float* mw1 = (const float*)d_in[8];
    const float* mb1 = (const float*)d_in[9];
    const float* mw2 = (const float*)d_in[10];
    const float* mb2 = (const float*)d_in[11];
    float* out = (float*)d_out;

    const int N = in_sizes[0] / HD;   // 50000
    const int E = in_sizes[1] / 2;    // 1600000

    char* p = (char*)d_ws;
    auto alloc = [&](size_t bytes) -> char* {
        char* q = p;
        p += (bytes + 255) & ~(size_t)255;
        return q;
    };
    int*   counts   = (int*)alloc((size_t)N * 4);
    int*   offsets  = (int*)alloc(((size_t)N + 1) * 4);
    int*   cursor   = (int*)alloc((size_t)N * 4);
    int*   partials = (int*)alloc(256 * 4);
    int*   sorted   = (int*)alloc((size_t)E * 4);
    float* Wt       = (float*)alloc((size_t)5 * HD * HD * 4);
    float* bufA     = (float*)alloc((size_t)N * HD * 4);
    float* bufB     = (float*)alloc((size_t)N * HD * 4);
    float* bufC     = (float*)alloc((size_t)N * HD * 4);

    const int nb = (N + 255) / 256;        // 196 (must be <= 256 for k_scan2)
    const int eb = (E + 255) / 256;
    const int gb = (N + 63) / 64;

    k_zero<<<nb, 256, 0, stream>>>(counts, N);
    k_count<<<eb, 256, 0, stream>>>(ei, E, counts);
    k_scan1<<<nb, 256, 0, stream>>>(counts, offsets, partials, N);
    k_scan2<<<1, 256, 0, stream>>>(partials, nb);
    k_scan3<<<nb, 256, 0, stream>>>(offsets, cursor, partials, N, E);
    k_scatter<<<eb, 256, 0, stream>>>(ei, E, cursor, sorted);

    k_transpose128<<<64, 256, 0, stream>>>(w1l, Wt + 0 * HD * HD);
    k_transpose128<<<64, 256, 0, stream>>>(w1r, Wt + 1 * HD * HD);
    k_transpose128<<<64, 256, 0, stream>>>(w2l, Wt + 2 * HD * HD);
    k_transpose128<<<64, 256, 0, stream>>>(w2r, Wt + 3 * HD * HD);
    k_transpose128<<<64, 256, 0, stream>>>(mw1, Wt + 4 * HD * HD);

    // layer 1
    k_aggr<<<N, 128, 0, stream>>>(x, offsets, sorted, bufA);
    k_gemm<true><<<gb, 256, 0, stream>>>(bufA, x, Wt + 0 * HD * HD, Wt + 1 * HD * HD,
                                         b1l, bufB, N);
    // layer 2
    k_aggr<<<N, 128, 0, stream>>>(bufB, offsets, sorted, bufA);
    k_gemm<true><<<gb, 256, 0, stream>>>(bufA, bufB, Wt + 2 * HD * HD, Wt + 3 * HD * HD,
                                         b2l, bufC, N);
    // MLP
    k_gemm<false><<<gb, 256, 0, stream>>>(bufC, nullptr, Wt + 4 * HD * HD, nullptr,
                                          mb1, bufA, N);
    k_final<<<nb, 256, 0, stream>>>(bufA, mw2, mb2, out, N);
}

// Round 2
// 635.358 us; speedup vs baseline: 1.1730x; 1.1730x over previous
//
#include <hip/hip_runtime.h>
#include <hip/hip_bf16.h>
#include <cstdint>

#define HD 128

// ---------------- CSR build ----------------

__global__ void k_zero(int* __restrict__ p, int n) {
    int i = blockIdx.x * 256 + threadIdx.x;
    if (i < n) p[i] = 0;
}

// count degree AND record each edge's rank within its dst bucket
__global__ void k_count(const int* __restrict__ ei, int E,
                        int* __restrict__ counts, int* __restrict__ rank) {
    int e = blockIdx.x * 256 + threadIdx.x;
    if (e < E) rank[e] = atomicAdd(&counts[ei[E + e]], 1);
}

__global__ void k_scan1(const int* __restrict__ counts, int* __restrict__ offsets,
                        int* __restrict__ partials, int n) {
    __shared__ int sh[256];
    int i = blockIdx.x * 256 + threadIdx.x;
    int v = (i < n) ? counts[i] : 0;
    sh[threadIdx.x] = v;
    __syncthreads();
    for (int d = 1; d < 256; d <<= 1) {
        int t = (threadIdx.x >= (unsigned)d) ? sh[threadIdx.x - d] : 0;
        __syncthreads();
        sh[threadIdx.x] += t;
        __syncthreads();
    }
    if (i < n) offsets[i] = sh[threadIdx.x] - v;        // exclusive
    if (threadIdx.x == 255) partials[blockIdx.x] = sh[255];
}

__global__ void k_scan2(int* __restrict__ partials, int nb) {
    __shared__ int sh[256];
    int v = (threadIdx.x < (unsigned)nb) ? partials[threadIdx.x] : 0;
    sh[threadIdx.x] = v;
    __syncthreads();
    for (int d = 1; d < 256; d <<= 1) {
        int t = (threadIdx.x >= (unsigned)d) ? sh[threadIdx.x - d] : 0;
        __syncthreads();
        sh[threadIdx.x] += t;
        __syncthreads();
    }
    if (threadIdx.x < (unsigned)nb) partials[threadIdx.x] = sh[threadIdx.x] - v;  // exclusive
}

__global__ void k_scan3(int* __restrict__ offsets, const int* __restrict__ partials,
                        int n, int total) {
    int i = blockIdx.x * 256 + threadIdx.x;
    if (i < n) offsets[i] += partials[blockIdx.x];
    if (i == 0) offsets[n] = total;
}

// atomic-free scatter: position fully determined by offsets[dst] + rank[e]
__global__ void k_scatter(const int* __restrict__ ei, int E,
                          const int* __restrict__ offsets, const int* __restrict__ rank,
                          int* __restrict__ sorted_src) {
    int e = blockIdx.x * 256 + threadIdx.x;
    if (e < E) {
        int s = ei[e];
        int d = ei[E + e];
        sorted_src[offsets[d] + rank[e]] = s;
    }
}

// ---------------- weight transpose (W[j][k] -> Wt[k][j]) ----------------

__global__ void k_transpose128(const float* __restrict__ w, float* __restrict__ wt) {
    int idx = blockIdx.x * 256 + threadIdx.x;   // 16384 elements, 64 blocks
    int j = idx >> 7, k = idx & 127;
    wt[k * HD + j] = w[idx];
}

// ---------------- mean aggregation (CSR gather) ----------------
// 256 threads per node: 8 edge-slots x 32 lanes x float4.
// 8 gather rows in flight -> latency hiding; float4 loads -> 4x fewer instrs.

__global__ __launch_bounds__(256) void k_aggr(const float* __restrict__ x,
                                              const int* __restrict__ offsets,
                                              const int* __restrict__ sorted_src,
                                              float* __restrict__ out) {
    int n = blockIdx.x;
    int q = threadIdx.x >> 5;     // edge slot 0..7
    int c = threadIdx.x & 31;     // feature quad 0..31
    int beg = offsets[n], end = offsets[n + 1];
    int deg = end - beg;

    __shared__ int sidx[256];
    __shared__ float4 red[256];

    float4 acc = make_float4(0.f, 0.f, 0.f, 0.f);
    for (int base = beg; base < end; base += 256) {
        int cnt = min(256, end - base);
        if (threadIdx.x < cnt) sidx[threadIdx.x] = sorted_src[base + threadIdx.x];
        __syncthreads();
        for (int e = q; e < cnt; e += 8) {
            const float4* row = (const float4*)(x + (size_t)sidx[e] * HD);
            float4 v = row[c];
            acc.x += v.x; acc.y += v.y; acc.z += v.z; acc.w += v.w;
        }
        __syncthreads();
    }
    red[threadIdx.x] = acc;
    __syncthreads();
    if (q < 4) {
        float4 o = red[threadIdx.x + 128];
        acc.x += o.x; acc.y += o.y; acc.z += o.z; acc.w += o.w;
        red[threadIdx.x] = acc;
    }
    __syncthreads();
    if (q < 2) {
        float4 o = red[threadIdx.x + 64];
        acc.x += o.x; acc.y += o.y; acc.z += o.z; acc.w += o.w;
        red[threadIdx.x] = acc;
    }
    __syncthreads();
    if (q == 0) {
        float4 o = red[threadIdx.x + 32];
        acc.x += o.x; acc.y += o.y; acc.z += o.z; acc.w += o.w;
        float inv = 1.f / fmaxf((float)deg, 1.0f);
        float4 r = make_float4(acc.x * inv, acc.y * inv, acc.z * inv, acc.w * inv);
        ((float4*)(out + (size_t)n * HD))[c] = r;
    }
}

// ---------------- fused (dual-)GEMM: out = relu(A@WlT + [B@WrT] + bias) ----------------

__device__ inline void fma4(float4& a, float s, float4 w) {
    a.x = fmaf(s, w.x, a.x);
    a.y = fmaf(s, w.y, a.y);
    a.z = fmaf(s, w.z, a.z);
    a.w = fmaf(s, w.w, a.w);
}

template <bool DUAL>
__global__ __launch_bounds__(256) void k_gemm(const float* __restrict__ A,
                                              const float* __restrict__ B,
                                              const float* __restrict__ WlT,
                                              const float* __restrict__ WrT,
                                              const float* __restrict__ bias,
                                              float* __restrict__ out, int nrows) {
    __shared__ float4 As[64 * 32];
    __shared__ float4 Bs[DUAL ? 64 * 32 : 1];
    int row0 = blockIdx.x * 64;

    for (int i = threadIdx.x; i < 64 * 32; i += 256) {
        int r = i >> 5;
        int row = row0 + r;
        float4 z = make_float4(0.f, 0.f, 0.f, 0.f);
        As[i] = (row < nrows) ? ((const float4*)A)[(size_t)row * 32 + (i & 31)] : z;
        if (DUAL)
            Bs[i] = (row < nrows) ? ((const float4*)B)[(size_t)row * 32 + (i & 31)] : z;
    }
    __syncthreads();

    int c  = threadIdx.x & 31;   // cols 4c..4c+3
    int rg = threadIdx.x >> 5;   // rows rg*8..rg*8+7
    float4 acc[8];
#pragma unroll
    for (int r = 0; r < 8; ++r) acc[r] = make_float4(0.f, 0.f, 0.f, 0.f);

    const float4* wl4 = (const float4*)WlT;
    const float4* wr4 = (const float4*)WrT;

#pragma unroll 4
    for (int k4 = 0; k4 < 32; ++k4) {
        float4 wl0 = wl4[(k4 * 4 + 0) * 32 + c];
        float4 wl1 = wl4[(k4 * 4 + 1) * 32 + c];
        float4 wl2 = wl4[(k4 * 4 + 2) * 32 + c];
        float4 wl3 = wl4[(k4 * 4 + 3) * 32 + c];
        float4 wr0, wr1, wr2, wr3;
        if (DUAL) {
            wr0 = wr4[(k4 * 4 + 0) * 32 + c];
            wr1 = wr4[(k4 * 4 + 1) * 32 + c];
            wr2 = wr4[(k4 * 4 + 2) * 32 + c];
            wr3 = wr4[(k4 * 4 + 3) * 32 + c];
        }
#pragma unroll
        for (int r = 0; r < 8; ++r) {
            float4 a = As[(rg * 8 + r) * 32 + k4];
            fma4(acc[r], a.x, wl0);
            fma4(acc[r], a.y, wl1);
            fma4(acc[r], a.z, wl2);
            fma4(acc[r], a.w, wl3);
            if (DUAL) {
                float4 b = Bs[(rg * 8 + r) * 32 + k4];
                fma4(acc[r], b.x, wr0);
                fma4(acc[r], b.y, wr1);
                fma4(acc[r], b.z, wr2);
                fma4(acc[r], b.w, wr3);
            }
        }
    }

    float4 b4 = ((const float4*)bias)[c];
#pragma unroll
    for (int r = 0; r < 8; ++r) {
        int row = row0 + rg * 8 + r;
        if (row < nrows) {
            float4 o;
            o.x = fmaxf(acc[r].x + b4.x, 0.f);
            o.y = fmaxf(acc[r].y + b4.y, 0.f);
            o.z = fmaxf(acc[r].z + b4.z, 0.f);
            o.w = fmaxf(acc[r].w + b4.w, 0.f);
            ((float4*)out)[(size_t)row * 32 + c] = o;
        }
    }
}

// ---------------- final: logits = h @ mw2.T + mb2 ----------------

__global__ void k_final(const float* __restrict__ h, const float* __restrict__ w,
                        const float* __restrict__ b, float* __restrict__ out, int n) {
    int i = blockIdx.x * 256 + threadIdx.x;
    if (i >= n) return;
    const float4* hp = (const float4*)(h + (size_t)i * HD);
    const float4* wp = (const float4*)w;   // uniform -> scalar loads
    float acc = 0.f;
#pragma unroll
    for (int k = 0; k < 32; ++k) {
        float4 hv = hp[k];
        float4 wv = wp[k];
        acc += hv.x * wv.x + hv.y * wv.y + hv.z * wv.z + hv.w * wv.w;
    }
    out[i] = acc + b[0];
}

// ---------------- launch ----------------

extern "C" void kernel_launch(void* const* d_in, const int* in_sizes, int n_in,
                              void* d_out, int out_size, void* d_ws, size_t ws_size,
                              hipStream_t stream) {
    const float* x   = (const float*)d_in[0];
    const int*   ei  = (const int*)d_in[1];   // [2,E] int32 (JAX x64 disabled)
    const float* w1l = (const float*)d_in[2];
    const float* b1l = (const float*)d_in[3];
    const float* w1r = (const float*)d_in[4];
    const float* w2l = (const float*)d_in[5];
    const float* b2l = (const float*)d_in[6];
    const float* w2r = (const float*)d_in[7];
    const float* mw1 = (const float*)d_in[8];
    const float* mb1 = (const float*)d_in[9];
    const float* mw2 = (const float*)d_in[10];
    const float* mb2 = (const float*)d_in[11];
    float* out = (float*)d_out;

    const int N = in_sizes[0] / HD;   // 50000
    const int E = in_sizes[1] / 2;    // 1600000

    char* p = (char*)d_ws;
    auto alloc = [&](size_t bytes) -> char* {
        char* q = p;
        p += (bytes + 255) & ~(size_t)255;
        return q;
    };
    int*   counts   = (int*)alloc((size_t)N * 4);
    int*   offsets  = (int*)alloc(((size_t)N + 1) * 4);
    int*   rank     = (int*)alloc((size_t)E * 4);
    int*   partials = (int*)alloc(256 * 4);
    int*   sorted   = (int*)alloc((size_t)E * 4);
    float* Wt       = (float*)alloc((size_t)5 * HD * HD * 4);
    float* bufA     = (float*)alloc((size_t)N * HD * 4);
    float* bufB     = (float*)alloc((size_t)N * HD * 4);
    float* bufC     = (float*)alloc((size_t)N * HD * 4);

    const int nb = (N + 255) / 256;        // 196 (must be <= 256 for k_scan2)
    const int eb = (E + 255) / 256;
    const int gb = (N + 63) / 64;

    k_zero<<<nb, 256, 0, stream>>>(counts, N);
    k_count<<<eb, 256, 0, stream>>>(ei, E, counts, rank);
    k_scan1<<<nb, 256, 0, stream>>>(counts, offsets, partials, N);
    k_scan2<<<1, 256, 0, stream>>>(partials, nb);
    k_scan3<<<nb, 256, 0, stream>>>(offsets, partials, N, E);
    k_scatter<<<eb, 256, 0, stream>>>(ei, E, offsets, rank, sorted);

    k_transpose128<<<64, 256, 0, stream>>>(w1l, Wt + 0 * HD * HD);
    k_transpose128<<<64, 256, 0, stream>>>(w1r, Wt + 1 * HD * HD);
    k_transpose128<<<64, 256, 0, stream>>>(w2l, Wt + 2 * HD * HD);
    k_transpose128<<<64, 256, 0, stream>>>(w2r, Wt + 3 * HD * HD);
    k_transpose128<<<64, 256, 0, stream>>>(mw1, Wt + 4 * HD * HD);

    // layer 1
    k_aggr<<<N, 256, 0, stream>>>(x, offsets, sorted, bufA);
    k_gemm<true><<<gb, 256, 0, stream>>>(bufA, x, Wt + 0 * HD * HD, Wt + 1 * HD * HD,
                                         b1l, bufB, N);
    // layer 2
    k_aggr<<<N, 256, 0, stream>>>(bufB, offsets, sorted, bufA);
    k_gemm<true><<<gb, 256, 0, stream>>>(bufA, bufB, Wt + 2 * HD * HD, Wt + 3 * HD * HD,
                                         b2l, bufC, N);
    // MLP
    k_gemm<false><<<gb, 256, 0, stream>>>(bufC, nullptr, Wt + 4 * HD * HD, nullptr,
                                          mb1, bufA, N);
    k_final<<<nb, 256, 0, stream>>>(bufA, mw2, mb2, out, N);
}

// Round 3
// 428.808 us; speedup vs baseline: 1.7380x; 1.4817x over previous
//
#include <hip/hip_runtime.h>
#include <hip/hip_bf16.h>
#include <cstdint>

#define HD 128

typedef __attribute__((ext_vector_type(8))) short bfx8;   // 8 bf16 in 4 VGPRs
typedef __attribute__((ext_vector_type(4))) float fx4;

__device__ inline float bf2f(short s) {
    union { uint32_t u; float f; } c;
    c.u = ((uint32_t)(unsigned short)s) << 16;
    return c.f;
}
__device__ inline unsigned short f2bf(float v) {
    union { float f; uint32_t u; } c;
    c.f = v;
    uint32_t u = c.u + 0x7FFF + ((c.u >> 16) & 1);   // RNE
    return (unsigned short)(u >> 16);
}

// ---------------- CSR build ----------------

__global__ void k_zero(int* __restrict__ p, int n) {
    int i = blockIdx.x * 256 + threadIdx.x;
    if (i < n) p[i] = 0;
}

__global__ void k_count(const int* __restrict__ ei, int E,
                        int* __restrict__ counts, int* __restrict__ rank) {
    int e = blockIdx.x * 256 + threadIdx.x;
    if (e < E) rank[e] = atomicAdd(&counts[ei[E + e]], 1);
}

__global__ void k_scan1(const int* __restrict__ counts, int* __restrict__ offsets,
                        int* __restrict__ partials, int n) {
    __shared__ int sh[256];
    int i = blockIdx.x * 256 + threadIdx.x;
    int v = (i < n) ? counts[i] : 0;
    sh[threadIdx.x] = v;
    __syncthreads();
    for (int d = 1; d < 256; d <<= 1) {
        int t = (threadIdx.x >= (unsigned)d) ? sh[threadIdx.x - d] : 0;
        __syncthreads();
        sh[threadIdx.x] += t;
        __syncthreads();
    }
    if (i < n) offsets[i] = sh[threadIdx.x] - v;        // exclusive
    if (threadIdx.x == 255) partials[blockIdx.x] = sh[255];
}

__global__ void k_scan2(int* __restrict__ partials, int nb) {
    __shared__ int sh[256];
    int v = (threadIdx.x < (unsigned)nb) ? partials[threadIdx.x] : 0;
    sh[threadIdx.x] = v;
    __syncthreads();
    for (int d = 1; d < 256; d <<= 1) {
        int t = (threadIdx.x >= (unsigned)d) ? sh[threadIdx.x - d] : 0;
        __syncthreads();
        sh[threadIdx.x] += t;
        __syncthreads();
    }
    if (threadIdx.x < (unsigned)nb) partials[threadIdx.x] = sh[threadIdx.x] - v;
}

__global__ void k_scan3(int* __restrict__ offsets, const int* __restrict__ partials,
                        int n, int total) {
    int i = blockIdx.x * 256 + threadIdx.x;
    if (i < n) offsets[i] += partials[blockIdx.x];
    if (i == 0) offsets[n] = total;
}

__global__ void k_scatter(const int* __restrict__ ei, int E,
                          const int* __restrict__ offsets, const int* __restrict__ rank,
                          int* __restrict__ sorted_src) {
    int e = blockIdx.x * 256 + threadIdx.x;
    if (e < E) {
        int s = ei[e];
        int d = ei[E + e];
        sorted_src[offsets[d] + rank[e]] = s;
    }
}

// ---------------- fp32 -> bf16 casts ----------------

__global__ void k_cast(const float* __restrict__ in, unsigned short* __restrict__ out,
                       int n8) {
    int i = blockIdx.x * 256 + threadIdx.x;
    if (i >= n8) return;
    float4 v0 = ((const float4*)in)[i * 2];
    float4 v1 = ((const float4*)in)[i * 2 + 1];
    bfx8 o;
    o[0] = (short)f2bf(v0.x); o[1] = (short)f2bf(v0.y);
    o[2] = (short)f2bf(v0.z); o[3] = (short)f2bf(v0.w);
    o[4] = (short)f2bf(v1.x); o[5] = (short)f2bf(v1.y);
    o[6] = (short)f2bf(v1.z); o[7] = (short)f2bf(v1.w);
    *(bfx8*)(out + (size_t)i * 8) = o;
}

// five 128x128 weights -> contiguous bf16 buffer (keeps native [out][k] layout)
__global__ void k_cast5(const float* __restrict__ w0, const float* __restrict__ w1,
                        const float* __restrict__ w2, const float* __restrict__ w3,
                        const float* __restrict__ w4, unsigned short* __restrict__ out) {
    int t = blockIdx.x * 256 + threadIdx.x;   // 10240 threads, 8 elems each
    if (t >= 5 * 2048) return;
    int w = t / 2048, j = t % 2048;
    const float* src = (w == 0) ? w0 : (w == 1) ? w1 : (w == 2) ? w2 : (w == 3) ? w3 : w4;
    float4 v0 = ((const float4*)src)[j * 2];
    float4 v1 = ((const float4*)src)[j * 2 + 1];
    bfx8 o;
    o[0] = (short)f2bf(v0.x); o[1] = (short)f2bf(v0.y);
    o[2] = (short)f2bf(v0.z); o[3] = (short)f2bf(v0.w);
    o[4] = (short)f2bf(v1.x); o[5] = (short)f2bf(v1.y);
    o[6] = (short)f2bf(v1.z); o[7] = (short)f2bf(v1.w);
    *(bfx8*)(out + (size_t)t * 8) = o;
}

// ---------------- mean aggregation (CSR gather, bf16 in/out) ----------------
// 256 threads per node: 16 edge-slots x 16 lanes x 16B (bf16x8).

__global__ __launch_bounds__(256) void k_aggr(const unsigned short* __restrict__ x,
                                              const int* __restrict__ offsets,
                                              const int* __restrict__ sorted_src,
                                              unsigned short* __restrict__ out) {
    int n = blockIdx.x;
    int q = threadIdx.x >> 4;     // edge slot 0..15
    int c = threadIdx.x & 15;     // feature octet 0..15
    int beg = offsets[n], end = offsets[n + 1];
    int deg = end - beg;

    __shared__ int sidx[256];
    __shared__ float red[16][HD];

    float acc[8];
#pragma unroll
    for (int j = 0; j < 8; ++j) acc[j] = 0.f;

    for (int base = beg; base < end; base += 256) {
        int cnt = min(256, end - base);
        if (threadIdx.x < cnt) sidx[threadIdx.x] = sorted_src[base + threadIdx.x];
        __syncthreads();
        for (int e = q; e < cnt; e += 16) {
            bfx8 v = *(const bfx8*)(x + (size_t)sidx[e] * HD + c * 8);
#pragma unroll
            for (int j = 0; j < 8; ++j) acc[j] += bf2f(v[j]);
        }
        __syncthreads();
    }
#pragma unroll
    for (int j = 0; j < 8; ++j) red[q][c * 8 + j] = acc[j];
    __syncthreads();
    for (int s = 8; s >= 1; s >>= 1) {
        if (q < s) {
#pragma unroll
            for (int j = 0; j < 8; ++j) red[q][c * 8 + j] += red[q + s][c * 8 + j];
        }
        __syncthreads();
    }
    if (q == 0) {
        float inv = 1.f / fmaxf((float)deg, 1.0f);
        bfx8 o;
#pragma unroll
        for (int j = 0; j < 8; ++j) o[j] = (short)f2bf(red[0][c * 8 + j] * inv);
        *(bfx8*)(out + (size_t)n * HD + c * 8) = o;
    }
}

// ---------------- MFMA (dual-)GEMM: out = relu(A@Wl^T + [B@Wr^T] + bias) ----------------
// 4 waves/block, 16 rows/wave, no LDS. Weights streamed from L1/L2 (64KB resident).
// mfma_f32_16x16x32_bf16: A lane: row=l&15, k=(l>>4)*8+j ; B lane: col=l&15, same k;
// D: col=l&15, row=(l>>4)*4+reg  [m89-verified]. W native [col_out][k] layout = B frag.

template <bool DUAL, bool FINAL>
__global__ __launch_bounds__(256) void k_gemm_mfma(
    const unsigned short* __restrict__ A,
    const unsigned short* __restrict__ B,
    const unsigned short* __restrict__ Wl,
    const unsigned short* __restrict__ Wr,
    const float* __restrict__ bias,
    unsigned short* __restrict__ outb,   // bf16 [nrows][128]   (!FINAL)
    float* __restrict__ outf,            // fp32 [nrows]        (FINAL)
    const float* __restrict__ mw2,       // [128]               (FINAL)
    const float* __restrict__ mb2,       // [1]                 (FINAL)
    int nrows) {
    int wid  = threadIdx.x >> 6;
    int lane = threadIdx.x & 63;
    int r  = lane & 15;
    int hi = lane >> 4;          // 0..3
    int ko = hi * 8;
    int row0 = blockIdx.x * 64 + wid * 16;

    int arow  = row0 + r;
    int arowc = min(arow, nrows - 1);    // clamp loads; stores guarded

    bfx8 a[4], b[4];
    const unsigned short* Ar = A + (size_t)arowc * HD;
#pragma unroll
    for (int kk = 0; kk < 4; ++kk)
        a[kk] = *(const bfx8*)(Ar + kk * 32 + ko);
    if (DUAL) {
        const unsigned short* Br = B + (size_t)arowc * HD;
#pragma unroll
        for (int kk = 0; kk < 4; ++kk)
            b[kk] = *(const bfx8*)(Br + kk * 32 + ko);
    }

    float pd[4];
    if (FINAL) { pd[0] = pd[1] = pd[2] = pd[3] = 0.f; }

#pragma unroll
    for (int cf = 0; cf < 8; ++cf) {
        fx4 acc = {0.f, 0.f, 0.f, 0.f};
        const unsigned short* wlp = Wl + (size_t)(cf * 16 + r) * HD + ko;
#pragma unroll
        for (int kk = 0; kk < 4; ++kk) {
            bfx8 wl = *(const bfx8*)(wlp + kk * 32);
            acc = __builtin_amdgcn_mfma_f32_16x16x32_bf16(a[kk], wl, acc, 0, 0, 0);
        }
        if (DUAL) {
            const unsigned short* wrp = Wr + (size_t)(cf * 16 + r) * HD + ko;
#pragma unroll
            for (int kk = 0; kk < 4; ++kk) {
                bfx8 wr = *(const bfx8*)(wrp + kk * 32);
                acc = __builtin_amdgcn_mfma_f32_16x16x32_bf16(b[kk], wr, acc, 0, 0, 0);
            }
        }
        float bv = bias[cf * 16 + r];
        if (FINAL) {
            float m = mw2[cf * 16 + r];
#pragma unroll
            for (int j = 0; j < 4; ++j)
                pd[j] += fmaxf(acc[j] + bv, 0.f) * m;
        } else {
#pragma unroll
            for (int j = 0; j < 4; ++j) {
                int row = row0 + hi * 4 + j;
                if (row < nrows)
                    outb[(size_t)row * HD + cf * 16 + r] = f2bf(fmaxf(acc[j] + bv, 0.f));
            }
        }
    }

    if (FINAL) {
        // reduce partial dots across the 16 lanes of each hi-group
#pragma unroll
        for (int s = 1; s < 16; s <<= 1) {
#pragma unroll
            for (int j = 0; j < 4; ++j)
                pd[j] += __shfl_xor(pd[j], s, 64);
        }
        if (r == 0) {
            float mb = mb2[0];
#pragma unroll
            for (int j = 0; j < 4; ++j) {
                int row = row0 + hi * 4 + j;
                if (row < nrows) outf[row] = pd[j] + mb;
            }
        }
    }
}

// ---------------- launch ----------------

extern "C" void kernel_launch(void* const* d_in, const int* in_sizes, int n_in,
                              void* d_out, int out_size, void* d_ws, size_t ws_size,
                              hipStream_t stream) {
    const float* x   = (const float*)d_in[0];
    const int*   ei  = (const int*)d_in[1];   // [2,E] int32
    const float* w1l = (const float*)d_in[2];
    const float* b1l = (const float*)d_in[3];
    const float* w1r = (const float*)d_in[4];
    const float* w2l = (const float*)d_in[5];
    const float* b2l = (const float*)d_in[6];
    const float* w2r = (const float*)d_in[7];
    const float* mw1 = (const float*)d_in[8];
    const float* mb1 = (const float*)d_in[9];
    const float* mw2 = (const float*)d_in[10];
    const float* mb2 = (const float*)d_in[11];
    float* out = (float*)d_out;

    const int N = in_sizes[0] / HD;   // 50000
    const int E = in_sizes[1] / 2;    // 1600000

    char* p = (char*)d_ws;
    auto alloc = [&](size_t bytes) -> char* {
        char* q = p;
        p += (bytes + 255) & ~(size_t)255;
        return q;
    };
    int*            counts   = (int*)alloc((size_t)N * 4);
    int*            offsets  = (int*)alloc(((size_t)N + 1) * 4);
    int*            rank     = (int*)alloc((size_t)E * 4);
    int*            partials = (int*)alloc(256 * 4);
    int*            sorted   = (int*)alloc((size_t)E * 4);
    unsigned short* Wtb      = (unsigned short*)alloc((size_t)5 * HD * HD * 2);
    unsigned short* xb       = (unsigned short*)alloc((size_t)N * HD * 2);
    unsigned short* bufA     = (unsigned short*)alloc((size_t)N * HD * 2);
    unsigned short* bufB     = (unsigned short*)alloc((size_t)N * HD * 2);
    unsigned short* bufC     = (unsigned short*)alloc((size_t)N * HD * 2);

    const unsigned short* W1l = Wtb + 0 * HD * HD;
    const unsigned short* W1r = Wtb + 1 * HD * HD;
    const unsigned short* W2l = Wtb + 2 * HD * HD;
    const unsigned short* W2r = Wtb + 3 * HD * HD;
    const unsigned short* Mw1 = Wtb + 4 * HD * HD;

    const int nb = (N + 255) / 256;        // 196 (<=256 for k_scan2)
    const int eb = (E + 255) / 256;
    const int gb = (N + 63) / 64;          // 782

    k_zero<<<nb, 256, 0, stream>>>(counts, N);
    k_count<<<eb, 256, 0, stream>>>(ei, E, counts, rank);
    k_scan1<<<nb, 256, 0, stream>>>(counts, offsets, partials, N);
    k_scan2<<<1, 256, 0, stream>>>(partials, nb);
    k_scan3<<<nb, 256, 0, stream>>>(offsets, partials, N, E);
    k_scatter<<<eb, 256, 0, stream>>>(ei, E, offsets, rank, sorted);

    k_cast<<<(N * HD / 8 + 255) / 256, 256, 0, stream>>>(x, xb, N * HD / 8);
    k_cast5<<<40, 256, 0, stream>>>(w1l, w1r, w2l, w2r, mw1, Wtb);

    // layer 1
    k_aggr<<<N, 256, 0, stream>>>(xb, offsets, sorted, bufA);
    k_gemm_mfma<true, false><<<gb, 256, 0, stream>>>(bufA, xb, W1l, W1r, b1l,
                                                     bufB, nullptr, nullptr, nullptr, N);
    // layer 2
    k_aggr<<<N, 256, 0, stream>>>(bufB, offsets, sorted, bufA);
    k_gemm_mfma<true, false><<<gb, 256, 0, stream>>>(bufA, bufB, W2l, W2r, b2l,
                                                     bufC, nullptr, nullptr, nullptr, N);
    // MLP + final dot fused
    k_gemm_mfma<false, true><<<gb, 256, 0, stream>>>(bufC, nullptr, Mw1, nullptr, mb1,
                                                     nullptr, out, mw2, mb2, N);
}

// Round 4
// 402.003 us; speedup vs baseline: 1.8539x; 1.0667x over previous
//
#include <hip/hip_runtime.h>
#include <hip/hip_bf16.h>
#include <cstdint>

#define HD 128

typedef __attribute__((ext_vector_type(8))) short bfx8;   // 8 bf16 in 4 VGPRs
typedef __attribute__((ext_vector_type(4))) float fx4;

__device__ inline float bf2f(short s) {
    union { uint32_t u; float f; } c;
    c.u = ((uint32_t)(unsigned short)s) << 16;
    return c.f;
}
__device__ inline unsigned short f2bf(float v) {
    union { float f; uint32_t u; } c;
    c.f = v;
    uint32_t u = c.u + 0x7FFF + ((c.u >> 16) & 1);   // RNE
    return (unsigned short)(u >> 16);
}

// ---------------- CSR build ----------------

__global__ void k_zero(int* __restrict__ p, int n) {
    int i = blockIdx.x * 256 + threadIdx.x;
    if (i < n) p[i] = 0;
}

__global__ void k_count(const int* __restrict__ ei, int E,
                        int* __restrict__ counts, int* __restrict__ rank) {
    int e = blockIdx.x * 256 + threadIdx.x;
    if (e < E) rank[e] = atomicAdd(&counts[ei[E + e]], 1);
}

__global__ void k_scan1(const int* __restrict__ counts, int* __restrict__ offsets,
                        int* __restrict__ partials, int n) {
    __shared__ int sh[256];
    int i = blockIdx.x * 256 + threadIdx.x;
    int v = (i < n) ? counts[i] : 0;
    sh[threadIdx.x] = v;
    __syncthreads();
    for (int d = 1; d < 256; d <<= 1) {
        int t = (threadIdx.x >= (unsigned)d) ? sh[threadIdx.x - d] : 0;
        __syncthreads();
        sh[threadIdx.x] += t;
        __syncthreads();
    }
    if (i < n) offsets[i] = sh[threadIdx.x] - v;        // exclusive
    if (threadIdx.x == 255) partials[blockIdx.x] = sh[255];
}

__global__ void k_scan2(int* __restrict__ partials, int nb) {
    __shared__ int sh[256];
    int v = (threadIdx.x < (unsigned)nb) ? partials[threadIdx.x] : 0;
    sh[threadIdx.x] = v;
    __syncthreads();
    for (int d = 1; d < 256; d <<= 1) {
        int t = (threadIdx.x >= (unsigned)d) ? sh[threadIdx.x - d] : 0;
        __syncthreads();
        sh[threadIdx.x] += t;
        __syncthreads();
    }
    if (threadIdx.x < (unsigned)nb) partials[threadIdx.x] = sh[threadIdx.x] - v;
}

__global__ void k_scan3(int* __restrict__ offsets, const int* __restrict__ partials,
                        int n, int total) {
    int i = blockIdx.x * 256 + threadIdx.x;
    if (i < n) offsets[i] += partials[blockIdx.x];
    if (i == 0) offsets[n] = total;
}

__global__ void k_scatter(const int* __restrict__ ei, int E,
                          const int* __restrict__ offsets, const int* __restrict__ rank,
                          int* __restrict__ sorted_src) {
    int e = blockIdx.x * 256 + threadIdx.x;
    if (e < E) {
        int s = ei[e];
        int d = ei[E + e];
        int pos = offsets[d] + rank[e];
        __builtin_nontemporal_store(s, &sorted_src[pos]);
    }
}

// ---------------- fp32 -> bf16 casts ----------------

__global__ void k_cast(const float* __restrict__ in, unsigned short* __restrict__ out,
                       int n8) {
    int i = blockIdx.x * 256 + threadIdx.x;
    if (i >= n8) return;
    float4 v0 = ((const float4*)in)[i * 2];
    float4 v1 = ((const float4*)in)[i * 2 + 1];
    bfx8 o;
    o[0] = (short)f2bf(v0.x); o[1] = (short)f2bf(v0.y);
    o[2] = (short)f2bf(v0.z); o[3] = (short)f2bf(v0.w);
    o[4] = (short)f2bf(v1.x); o[5] = (short)f2bf(v1.y);
    o[6] = (short)f2bf(v1.z); o[7] = (short)f2bf(v1.w);
    *(bfx8*)(out + (size_t)i * 8) = o;
}

__global__ void k_cast5(const float* __restrict__ w0, const float* __restrict__ w1,
                        const float* __restrict__ w2, const float* __restrict__ w3,
                        const float* __restrict__ w4, unsigned short* __restrict__ out) {
    int t = blockIdx.x * 256 + threadIdx.x;   // 10240 threads, 8 elems each
    if (t >= 5 * 2048) return;
    int w = t / 2048, j = t % 2048;
    const float* src = (w == 0) ? w0 : (w == 1) ? w1 : (w == 2) ? w2 : (w == 3) ? w3 : w4;
    float4 v0 = ((const float4*)src)[j * 2];
    float4 v1 = ((const float4*)src)[j * 2 + 1];
    bfx8 o;
    o[0] = (short)f2bf(v0.x); o[1] = (short)f2bf(v0.y);
    o[2] = (short)f2bf(v0.z); o[3] = (short)f2bf(v0.w);
    o[4] = (short)f2bf(v1.x); o[5] = (short)f2bf(v1.y);
    o[6] = (short)f2bf(v1.z); o[7] = (short)f2bf(v1.w);
    *(bfx8*)(out + (size_t)t * 8) = o;
}

// ---------------- mean aggregation: one wave per node, shfl reduce ----------------
// 4 waves/block = 4 nodes. Per wave: 4 edge-slots x 16 lanes x bfx8 (16B).
// Mean degree 32 -> ~4 unrolled gather iterations; no LDS at all.

__global__ __launch_bounds__(256) void k_aggr(const unsigned short* __restrict__ x,
                                              const int* __restrict__ offsets,
                                              const int* __restrict__ sorted_src,
                                              unsigned short* __restrict__ out, int N) {
    int wid  = threadIdx.x >> 6;
    int lane = threadIdx.x & 63;
    int n = blockIdx.x * 4 + wid;
    if (n >= N) return;
    int slot = lane >> 4;     // 0..3
    int c    = lane & 15;     // feature octet
    int beg = offsets[n], end = offsets[n + 1];

    float acc[8];
#pragma unroll
    for (int j = 0; j < 8; ++j) acc[j] = 0.f;

    int e = beg + slot;
    for (; e + 4 < end; e += 8) {
        int i0 = sorted_src[e];
        int i1 = sorted_src[e + 4];
        bfx8 v0 = *(const bfx8*)(x + (size_t)i0 * HD + c * 8);
        bfx8 v1 = *(const bfx8*)(x + (size_t)i1 * HD + c * 8);
#pragma unroll
        for (int j = 0; j < 8; ++j) acc[j] += bf2f(v0[j]);
#pragma unroll
        for (int j = 0; j < 8; ++j) acc[j] += bf2f(v1[j]);
    }
    if (e < end) {
        int i0 = sorted_src[e];
        bfx8 v0 = *(const bfx8*)(x + (size_t)i0 * HD + c * 8);
#pragma unroll
        for (int j = 0; j < 8; ++j) acc[j] += bf2f(v0[j]);
    }

#pragma unroll
    for (int j = 0; j < 8; ++j) {
        acc[j] += __shfl_xor(acc[j], 16, 64);
        acc[j] += __shfl_xor(acc[j], 32, 64);
    }
    if (slot == 0) {
        float inv = 1.f / fmaxf((float)(end - beg), 1.f);
        bfx8 o;
#pragma unroll
        for (int j = 0; j < 8; ++j) o[j] = (short)f2bf(acc[j] * inv);
        *(bfx8*)(out + (size_t)n * HD + c * 8) = o;
    }
}

// ---------------- layer-1 MFMA dual GEMM: bufB = relu(A@Wl^T + B@Wr^T + b) ----------------
// mfma_f32_16x16x32_bf16: A lane: row=l&15, k=(l>>4)*8+j ; B lane: col=l&15 ;
// D: col=l&15, row=(l>>4)*4+reg  [m89-verified]. W native [out][k] = B frag directly.

__global__ __launch_bounds__(256) void k_gemm_mfma(
    const unsigned short* __restrict__ A,
    const unsigned short* __restrict__ B,
    const unsigned short* __restrict__ Wl,
    const unsigned short* __restrict__ Wr,
    const float* __restrict__ bias,
    unsigned short* __restrict__ outb, int nrows) {
    int wid  = threadIdx.x >> 6;
    int lane = threadIdx.x & 63;
    int r  = lane & 15;
    int hi = lane >> 4;          // 0..3
    int ko = hi * 8;
    int row0 = blockIdx.x * 64 + wid * 16;

    int arow  = row0 + r;
    int arowc = min(arow, nrows - 1);

    bfx8 a[4], b[4];
    const unsigned short* Ar = A + (size_t)arowc * HD;
    const unsigned short* Br = B + (size_t)arowc * HD;
#pragma unroll
    for (int kk = 0; kk < 4; ++kk) {
        a[kk] = *(const bfx8*)(Ar + kk * 32 + ko);
        b[kk] = *(const bfx8*)(Br + kk * 32 + ko);
    }

#pragma unroll
    for (int cf = 0; cf < 8; ++cf) {
        fx4 acc = {0.f, 0.f, 0.f, 0.f};
        const unsigned short* wlp = Wl + (size_t)(cf * 16 + r) * HD + ko;
        const unsigned short* wrp = Wr + (size_t)(cf * 16 + r) * HD + ko;
#pragma unroll
        for (int kk = 0; kk < 4; ++kk) {
            bfx8 wl = *(const bfx8*)(wlp + kk * 32);
            acc = __builtin_amdgcn_mfma_f32_16x16x32_bf16(a[kk], wl, acc, 0, 0, 0);
        }
#pragma unroll
        for (int kk = 0; kk < 4; ++kk) {
            bfx8 wr = *(const bfx8*)(wrp + kk * 32);
            acc = __builtin_amdgcn_mfma_f32_16x16x32_bf16(b[kk], wr, acc, 0, 0, 0);
        }
        float bv = bias[cf * 16 + r];
#pragma unroll
        for (int j = 0; j < 4; ++j) {
            int row = row0 + hi * 4 + j;
            if (row < nrows)
                outb[(size_t)row * HD + cf * 16 + r] = f2bf(fmaxf(acc[j] + bv, 0.f));
        }
    }
}

// ---------------- fused layer2 + MLP + final dot ----------------
// Stage 1: h2 = relu(aggr2@W2l^T + h1@W2r^T + b2)  -> LDS (bf16, XOR-swizzled)
// Stage 2: h3 = relu(h2@Mw1^T + mb1); logit = h3 . mw2 + mb2 (shfl-reduced)
// LDS swizzle: byte ^= (row&7)<<4 — spreads the stage-2 b128 column-slice reads
// evenly over all 32 banks (unswizzled would serialize 16-way).

__global__ __launch_bounds__(256) void k_l2_fused(
    const unsigned short* __restrict__ A,     // aggr2
    const unsigned short* __restrict__ B,     // h1
    const unsigned short* __restrict__ Wl,    // w2l
    const unsigned short* __restrict__ Wr,    // w2r
    const float* __restrict__ bias,           // b2l
    const unsigned short* __restrict__ Mw1,   // mw1 bf16
    const float* __restrict__ mb1,
    const float* __restrict__ mw2,
    const float* __restrict__ mb2,
    float* __restrict__ outf, int nrows) {
    __shared__ unsigned short hlds[64 * HD];   // 16 KB

    int wid  = threadIdx.x >> 6;
    int lane = threadIdx.x & 63;
    int r  = lane & 15;
    int hi = lane >> 4;
    int ko = hi * 8;
    int row0 = blockIdx.x * 64 + wid * 16;

    int arow  = row0 + r;
    int arowc = min(arow, nrows - 1);

    bfx8 a[4], b[4];
    const unsigned short* Ar = A + (size_t)arowc * HD;
    const unsigned short* Br = B + (size_t)arowc * HD;
#pragma unroll
    for (int kk = 0; kk < 4; ++kk) {
        a[kk] = *(const bfx8*)(Ar + kk * 32 + ko);
        b[kk] = *(const bfx8*)(Br + kk * 32 + ko);
    }

    // ---- stage 1: h2 tile into LDS ----
#pragma unroll
    for (int cf = 0; cf < 8; ++cf) {
        fx4 acc = {0.f, 0.f, 0.f, 0.f};
        const unsigned short* wlp = Wl + (size_t)(cf * 16 + r) * HD + ko;
        const unsigned short* wrp = Wr + (size_t)(cf * 16 + r) * HD + ko;
#pragma unroll
        for (int kk = 0; kk < 4; ++kk) {
            bfx8 wl = *(const bfx8*)(wlp + kk * 32);
            acc = __builtin_amdgcn_mfma_f32_16x16x32_bf16(a[kk], wl, acc, 0, 0, 0);
        }
#pragma unroll
        for (int kk = 0; kk < 4; ++kk) {
            bfx8 wr = *(const bfx8*)(wrp + kk * 32);
            acc = __builtin_amdgcn_mfma_f32_16x16x32_bf16(b[kk], wr, acc, 0, 0, 0);
        }
        float bv = bias[cf * 16 + r];
#pragma unroll
        for (int j = 0; j < 4; ++j) {
            int row_l = wid * 16 + hi * 4 + j;        // 0..63 (block-local)
            unsigned boff = (unsigned)(row_l * 256 + (cf * 16 + r) * 2);
            boff ^= (unsigned)((row_l & 7) << 4);
            *(unsigned short*)((char*)hlds + boff) = f2bf(fmaxf(acc[j] + bv, 0.f));
        }
    }
    __syncthreads();

    // ---- stage 2: A-frags of h2 from LDS, GEMM vs Mw1, fused mw2 dot ----
    bfx8 af[4];
    {
        int row_l = wid * 16 + r;                     // this wave's own rows
#pragma unroll
        for (int kk = 0; kk < 4; ++kk) {
            unsigned boff = (unsigned)(row_l * 256 + (kk * 32 + ko) * 2);
            boff ^= (unsigned)((row_l & 7) << 4);
            af[kk] = *(const bfx8*)((char*)hlds + boff);
        }
    }

    float pd[4] = {0.f, 0.f, 0.f, 0.f};
#pragma unroll
    for (int cf = 0; cf < 8; ++cf) {
        fx4 acc = {0.f, 0.f, 0.f, 0.f};
        const unsigned short* wp = Mw1 + (size_t)(cf * 16 + r) * HD + ko;
#pragma unroll
        for (int kk = 0; kk < 4; ++kk) {
            bfx8 w = *(const bfx8*)(wp + kk * 32);
            acc = __builtin_amdgcn_mfma_f32_16x16x32_bf16(af[kk], w, acc, 0, 0, 0);
        }
        float bv = mb1[cf * 16 + r];
        float m  = mw2[cf * 16 + r];
#pragma unroll
        for (int j = 0; j < 4; ++j)
            pd[j] += fmaxf(acc[j] + bv, 0.f) * m;
    }

#pragma unroll
    for (int s = 1; s < 16; s <<= 1) {
#pragma unroll
        for (int j = 0; j < 4; ++j)
            pd[j] += __shfl_xor(pd[j], s, 64);
    }
    if (r == 0) {
        float mb = mb2[0];
#pragma unroll
        for (int j = 0; j < 4; ++j) {
            int row = row0 + hi * 4 + j;
            if (row < nrows) outf[row] = pd[j] + mb;
        }
    }
}

// ---------------- launch ----------------

extern "C" void kernel_launch(void* const* d_in, const int* in_sizes, int n_in,
                              void* d_out, int out_size, void* d_ws, size_t ws_size,
                              hipStream_t stream) {
    const float* x   = (const float*)d_in[0];
    const int*   ei  = (const int*)d_in[1];   // [2,E] int32
    const float* w1l = (const float*)d_in[2];
    const float* b1l = (const float*)d_in[3];
    const float* w1r = (const float*)d_in[4];
    const float* w2l = (const float*)d_in[5];
    const float* b2l = (const float*)d_in[6];
    const float* w2r = (const float*)d_in[7];
    const float* mw1 = (const float*)d_in[8];
    const float* mb1 = (const float*)d_in[9];
    const float* mw2 = (const float*)d_in[10];
    const float* mb2 = (const float*)d_in[11];
    float* out = (float*)d_out;

    const int N = in_sizes[0] / HD;   // 50000
    const int E = in_sizes[1] / 2;    // 1600000

    char* p = (char*)d_ws;
    auto alloc = [&](size_t bytes) -> char* {
        char* q = p;
        p += (bytes + 255) & ~(size_t)255;
        return q;
    };
    int*            counts   = (int*)alloc((size_t)N * 4);
    int*            offsets  = (int*)alloc(((size_t)N + 1) * 4);
    int*            rank     = (int*)alloc((size_t)E * 4);
    int*            partials = (int*)alloc(256 * 4);
    int*            sorted   = (int*)alloc((size_t)E * 4);
    unsigned short* Wtb      = (unsigned short*)alloc((size_t)5 * HD * HD * 2);
    unsigned short* xb       = (unsigned short*)alloc((size_t)N * HD * 2);
    unsigned short* bufA     = (unsigned short*)alloc((size_t)N * HD * 2);
    unsigned short* bufB     = (unsigned short*)alloc((size_t)N * HD * 2);

    const unsigned short* W1l = Wtb + 0 * HD * HD;
    const unsigned short* W1r = Wtb + 1 * HD * HD;
    const unsigned short* W2l = Wtb + 2 * HD * HD;
    const unsigned short* W2r = Wtb + 3 * HD * HD;
    const unsigned short* Mw1 = Wtb + 4 * HD * HD;

    const int nb = (N + 255) / 256;        // 196 (<=256 for k_scan2)
    const int eb = (E + 255) / 256;
    const int gb = (N + 63) / 64;          // 782
    const int ab = (N + 3) / 4;            // 12500

    k_zero<<<nb, 256, 0, stream>>>(counts, N);
    k_count<<<eb, 256, 0, stream>>>(ei, E, counts, rank);
    k_scan1<<<nb, 256, 0, stream>>>(counts, offsets, partials, N);
    k_scan2<<<1, 256, 0, stream>>>(partials, nb);
    k_scan3<<<nb, 256, 0, stream>>>(offsets, partials, N, E);
    k_scatter<<<eb, 256, 0, stream>>>(ei, E, offsets, rank, sorted);

    k_cast<<<(N * HD / 8 + 255) / 256, 256, 0, stream>>>(x, xb, N * HD / 8);
    k_cast5<<<40, 256, 0, stream>>>(w1l, w1r, w2l, w2r, mw1, Wtb);

    // layer 1
    k_aggr<<<ab, 256, 0, stream>>>(xb, offsets, sorted, bufA, N);
    k_gemm_mfma<<<gb, 256, 0, stream>>>(bufA, xb, W1l, W1r, b1l, bufB, N);
    // layer 2 aggr
    k_aggr<<<ab, 256, 0, stream>>>(bufB, offsets, sorted, bufA, N);
    // layer 2 GEMM + MLP + final, fused
    k_l2_fused<<<gb, 256, 0, stream>>>(bufA, bufB, W2l, W2r, b2l, Mw1, mb1, mw2, mb2,
                                       out, N);
}

// Round 5
// 334.177 us; speedup vs baseline: 2.2302x; 1.2030x over previous
//
#include <hip/hip_runtime.h>
#include <hip/hip_bf16.h>
#include <cstdint>

#define HD 128
#define CAP 4096          // bucket capacity (mean fill 2048, ~45 sigma headroom)

typedef __attribute__((ext_vector_type(8))) short bfx8;   // 8 bf16 in 4 VGPRs
typedef __attribute__((ext_vector_type(4))) float fx4;

__device__ inline float bf2f(short s) {
    union { uint32_t u; float f; } c;
    c.u = ((uint32_t)(unsigned short)s) << 16;
    return c.f;
}
__device__ inline unsigned short f2bf(float v) {
    union { float f; uint32_t u; } c;
    c.f = v;
    uint32_t u = c.u + 0x7FFF + ((c.u >> 16) & 1);   // RNE
    return (unsigned short)(u >> 16);
}

// ---------------- bucketed CSR build ----------------
// bucket b = dst >> 6 (64 nodes per bucket, NBK = ceil(N/64) = 782).

__global__ void k_zero(int* __restrict__ p, int n) {
    int i = blockIdx.x * 256 + threadIdx.x;
    if (i < n) p[i] = 0;
}

// Phase 1: LDS-aggregated binning. One global atomic per (block,bucket) instead
// of one per edge (~300K vs 1.6M coherent-point transactions).
__global__ __launch_bounds__(256) void k_bin(const int* __restrict__ ei, int E, int NBK,
                                             int* __restrict__ bcnt,
                                             int* __restrict__ bsrc,
                                             int* __restrict__ bdst) {
    __shared__ int lhist[800];
    __shared__ int gbase[800];
    int base = blockIdx.x * 4096;

    for (int i = threadIdx.x; i < NBK; i += 256) lhist[i] = 0;
    __syncthreads();

    unsigned short bv[16], lrv[16];
#pragma unroll
    for (int i = 0; i < 16; ++i) {
        int e = base + i * 256 + threadIdx.x;
        bv[i] = 0xFFFF;
        if (e < E) {
            int d = ei[E + e];
            int b = d >> 6;
            int lr = atomicAdd(&lhist[b], 1);    // LDS atomic: cheap
            bv[i] = (unsigned short)b;
            lrv[i] = (unsigned short)lr;
        }
    }
    __syncthreads();
    for (int i = threadIdx.x; i < NBK; i += 256) {
        int c = lhist[i];
        gbase[i] = c ? atomicAdd(&bcnt[i], c) : 0;   // one global atomic per bucket
    }
    __syncthreads();
#pragma unroll
    for (int i = 0; i < 16; ++i) {
        int e = base + i * 256 + threadIdx.x;
        if (e < E) {
            int b = bv[i];
            int pos = b * CAP + min(gbase[b] + (int)lrv[i], CAP - 1); // clamp: no OOB
            bsrc[pos] = ei[e];
            bdst[pos] = ei[E + e];
        }
    }
}

// Phase 2: exclusive scan of bucket counts (NBK <= 1024, one block)
__global__ __launch_bounds__(1024) void k_bscan(const int* __restrict__ bcnt,
                                                int* __restrict__ boff, int NBK, int E) {
    __shared__ int sh[1024];
    int t = threadIdx.x;
    int v = (t < NBK) ? bcnt[t] : 0;
    sh[t] = v;
    __syncthreads();
    for (int d = 1; d < 1024; d <<= 1) {
        int o = (t >= d) ? sh[t - d] : 0;
        __syncthreads();
        sh[t] += o;
        __syncthreads();
    }
    if (t < NBK) boff[t] = sh[t] - v;     // exclusive
    if (t == 0) boff[NBK] = E;
}

// Phase 3: per-bucket local sort. LDS atomics only; sorted-array lines are
// written entirely by one block -> no cross-XCD line bouncing.
__global__ __launch_bounds__(256) void k_bucket(const int* __restrict__ bsrc,
                                                const int* __restrict__ bdst,
                                                const int* __restrict__ bcnt,
                                                const int* __restrict__ boff,
                                                int* __restrict__ offsets,
                                                int* __restrict__ sorted,
                                                int N, int E) {
    __shared__ int lh[64];
    __shared__ int cur[64];
    int b = blockIdx.x;
    int cnt = min(bcnt[b], CAP);
    int base = b * CAP;
    int obase = boff[b];

    if (threadIdx.x < 64) lh[threadIdx.x] = 0;
    __syncthreads();
    for (int i = threadIdx.x; i < cnt; i += 256)
        atomicAdd(&lh[bdst[base + i] & 63], 1);
    __syncthreads();
    if (threadIdx.x < 64) {          // wave 0: inclusive shfl-scan over 64 lanes
        int v = lh[threadIdx.x];
        int sum = v;
#pragma unroll
        for (int s = 1; s < 64; s <<= 1) {
            int o = __shfl_up(sum, s, 64);
            if ((int)threadIdx.x >= s) sum += o;
        }
        int excl = sum - v;
        int n = b * 64 + threadIdx.x;
        if (n < N) offsets[n] = obase + excl;
        cur[threadIdx.x] = excl;
    }
    __syncthreads();
    for (int i = threadIdx.x; i < cnt; i += 256) {
        int d = bdst[base + i];
        int s = bsrc[base + i];
        int p = atomicAdd(&cur[d & 63], 1);      // LDS atomic
        sorted[obase + p] = s;
    }
    if (b == 0 && threadIdx.x == 0) offsets[N] = E;
}

// ---------------- fp32 -> bf16 casts ----------------

__global__ void k_cast(const float* __restrict__ in, unsigned short* __restrict__ out,
                       int n8) {
    int i = blockIdx.x * 256 + threadIdx.x;
    if (i >= n8) return;
    float4 v0 = ((const float4*)in)[i * 2];
    float4 v1 = ((const float4*)in)[i * 2 + 1];
    bfx8 o;
    o[0] = (short)f2bf(v0.x); o[1] = (short)f2bf(v0.y);
    o[2] = (short)f2bf(v0.z); o[3] = (short)f2bf(v0.w);
    o[4] = (short)f2bf(v1.x); o[5] = (short)f2bf(v1.y);
    o[6] = (short)f2bf(v1.z); o[7] = (short)f2bf(v1.w);
    *(bfx8*)(out + (size_t)i * 8) = o;
}

__global__ void k_cast5(const float* __restrict__ w0, const float* __restrict__ w1,
                        const float* __restrict__ w2, const float* __restrict__ w3,
                        const float* __restrict__ w4, unsigned short* __restrict__ out) {
    int t = blockIdx.x * 256 + threadIdx.x;   // 10240 threads, 8 elems each
    if (t >= 5 * 2048) return;
    int w = t / 2048, j = t % 2048;
    const float* src = (w == 0) ? w0 : (w == 1) ? w1 : (w == 2) ? w2 : (w == 3) ? w3 : w4;
    float4 v0 = ((const float4*)src)[j * 2];
    float4 v1 = ((const float4*)src)[j * 2 + 1];
    bfx8 o;
    o[0] = (short)f2bf(v0.x); o[1] = (short)f2bf(v0.y);
    o[2] = (short)f2bf(v0.z); o[3] = (short)f2bf(v0.w);
    o[4] = (short)f2bf(v1.x); o[5] = (short)f2bf(v1.y);
    o[6] = (short)f2bf(v1.z); o[7] = (short)f2bf(v1.w);
    *(bfx8*)(out + (size_t)t * 8) = o;
}

// ---------------- mean aggregation: one wave per node, shfl reduce ----------------

__global__ __launch_bounds__(256) void k_aggr(const unsigned short* __restrict__ x,
                                              const int* __restrict__ offsets,
                                              const int* __restrict__ sorted_src,
                                              unsigned short* __restrict__ out, int N) {
    int wid  = threadIdx.x >> 6;
    int lane = threadIdx.x & 63;
    int n = blockIdx.x * 4 + wid;
    if (n >= N) return;
    int slot = lane >> 4;     // 0..3
    int c    = lane & 15;     // feature octet
    int beg = offsets[n], end = offsets[n + 1];

    float acc[8];
#pragma unroll
    for (int j = 0; j < 8; ++j) acc[j] = 0.f;

    int e = beg + slot;
    for (; e + 4 < end; e += 8) {
        int i0 = sorted_src[e];
        int i1 = sorted_src[e + 4];
        bfx8 v0 = *(const bfx8*)(x + (size_t)i0 * HD + c * 8);
        bfx8 v1 = *(const bfx8*)(x + (size_t)i1 * HD + c * 8);
#pragma unroll
        for (int j = 0; j < 8; ++j) acc[j] += bf2f(v0[j]);
#pragma unroll
        for (int j = 0; j < 8; ++j) acc[j] += bf2f(v1[j]);
    }
    if (e < end) {
        int i0 = sorted_src[e];
        bfx8 v0 = *(const bfx8*)(x + (size_t)i0 * HD + c * 8);
#pragma unroll
        for (int j = 0; j < 8; ++j) acc[j] += bf2f(v0[j]);
    }

#pragma unroll
    for (int j = 0; j < 8; ++j) {
        acc[j] += __shfl_xor(acc[j], 16, 64);
        acc[j] += __shfl_xor(acc[j], 32, 64);
    }
    if (slot == 0) {
        float inv = 1.f / fmaxf((float)(end - beg), 1.f);
        bfx8 o;
#pragma unroll
        for (int j = 0; j < 8; ++j) o[j] = (short)f2bf(acc[j] * inv);
        *(bfx8*)(out + (size_t)n * HD + c * 8) = o;
    }
}

// ---------------- layer-1 MFMA dual GEMM ----------------
// mfma_f32_16x16x32_bf16: A lane: row=l&15, k=(l>>4)*8+j ; B lane: col=l&15 ;
// D: col=l&15, row=(l>>4)*4+reg  [m89-verified]. W native [out][k] = B frag directly.

__global__ __launch_bounds__(256) void k_gemm_mfma(
    const unsigned short* __restrict__ A,
    const unsigned short* __restrict__ B,
    const unsigned short* __restrict__ Wl,
    const unsigned short* __restrict__ Wr,
    const float* __restrict__ bias,
    unsigned short* __restrict__ outb, int nrows) {
    int wid  = threadIdx.x >> 6;
    int lane = threadIdx.x & 63;
    int r  = lane & 15;
    int hi = lane >> 4;          // 0..3
    int ko = hi * 8;
    int row0 = blockIdx.x * 64 + wid * 16;

    int arow  = row0 + r;
    int arowc = min(arow, nrows - 1);

    bfx8 a[4], b[4];
    const unsigned short* Ar = A + (size_t)arowc * HD;
    const unsigned short* Br = B + (size_t)arowc * HD;
#pragma unroll
    for (int kk = 0; kk < 4; ++kk) {
        a[kk] = *(const bfx8*)(Ar + kk * 32 + ko);
        b[kk] = *(const bfx8*)(Br + kk * 32 + ko);
    }

#pragma unroll
    for (int cf = 0; cf < 8; ++cf) {
        fx4 acc = {0.f, 0.f, 0.f, 0.f};
        const unsigned short* wlp = Wl + (size_t)(cf * 16 + r) * HD + ko;
        const unsigned short* wrp = Wr + (size_t)(cf * 16 + r) * HD + ko;
#pragma unroll
        for (int kk = 0; kk < 4; ++kk) {
            bfx8 wl = *(const bfx8*)(wlp + kk * 32);
            acc = __builtin_amdgcn_mfma_f32_16x16x32_bf16(a[kk], wl, acc, 0, 0, 0);
        }
#pragma unroll
        for (int kk = 0; kk < 4; ++kk) {
            bfx8 wr = *(const bfx8*)(wrp + kk * 32);
            acc = __builtin_amdgcn_mfma_f32_16x16x32_bf16(b[kk], wr, acc, 0, 0, 0);
        }
        float bv = bias[cf * 16 + r];
#pragma unroll
        for (int j = 0; j < 4; ++j) {
            int row = row0 + hi * 4 + j;
            if (row < nrows)
                outb[(size_t)row * HD + cf * 16 + r] = f2bf(fmaxf(acc[j] + bv, 0.f));
        }
    }
}

// ---------------- fused layer2 + MLP + final dot ----------------
// LDS swizzle: byte ^= (row&7)<<4 spreads stage-2 b128 column reads over banks.

__global__ __launch_bounds__(256) void k_l2_fused(
    const unsigned short* __restrict__ A,     // aggr2
    const unsigned short* __restrict__ B,     // h1
    const unsigned short* __restrict__ Wl,    // w2l
    const unsigned short* __restrict__ Wr,    // w2r
    const float* __restrict__ bias,           // b2l
    const unsigned short* __restrict__ Mw1,   // mw1 bf16
    const float* __restrict__ mb1,
    const float* __restrict__ mw2,
    const float* __restrict__ mb2,
    float* __restrict__ outf, int nrows) {
    __shared__ unsigned short hlds[64 * HD];   // 16 KB

    int wid  = threadIdx.x >> 6;
    int lane = threadIdx.x & 63;
    int r  = lane & 15;
    int hi = lane >> 4;
    int ko = hi * 8;
    int row0 = blockIdx.x * 64 + wid * 16;

    int arow  = row0 + r;
    int arowc = min(arow, nrows - 1);

    bfx8 a[4], b[4];
    const unsigned short* Ar = A + (size_t)arowc * HD;
    const unsigned short* Br = B + (size_t)arowc * HD;
#pragma unroll
    for (int kk = 0; kk < 4; ++kk) {
        a[kk] = *(const bfx8*)(Ar + kk * 32 + ko);
        b[kk] = *(const bfx8*)(Br + kk * 32 + ko);
    }

    // ---- stage 1: h2 tile into LDS ----
#pragma unroll
    for (int cf = 0; cf < 8; ++cf) {
        fx4 acc = {0.f, 0.f, 0.f, 0.f};
        const unsigned short* wlp = Wl + (size_t)(cf * 16 + r) * HD + ko;
        const unsigned short* wrp = Wr + (size_t)(cf * 16 + r) * HD + ko;
#pragma unroll
        for (int kk = 0; kk < 4; ++kk) {
            bfx8 wl = *(const bfx8*)(wlp + kk * 32);
            acc = __builtin_amdgcn_mfma_f32_16x16x32_bf16(a[kk], wl, acc, 0, 0, 0);
        }
#pragma unroll
        for (int kk = 0; kk < 4; ++kk) {
            bfx8 wr = *(const bfx8*)(wrp + kk * 32);
            acc = __builtin_amdgcn_mfma_f32_16x16x32_bf16(b[kk], wr, acc, 0, 0, 0);
        }
        float bv = bias[cf * 16 + r];
#pragma unroll
        for (int j = 0; j < 4; ++j) {
            int row_l = wid * 16 + hi * 4 + j;        // 0..63 block-local
            unsigned boff = (unsigned)(row_l * 256 + (cf * 16 + r) * 2);
            boff ^= (unsigned)((row_l & 7) << 4);
            *(unsigned short*)((char*)hlds + boff) = f2bf(fmaxf(acc[j] + bv, 0.f));
        }
    }
    __syncthreads();

    // ---- stage 2: h2 A-frags from LDS, GEMM vs Mw1, fused mw2 dot ----
    bfx8 af[4];
    {
        int row_l = wid * 16 + r;
#pragma unroll
        for (int kk = 0; kk < 4; ++kk) {
            unsigned boff = (unsigned)(row_l * 256 + (kk * 32 + ko) * 2);
            boff ^= (unsigned)((row_l & 7) << 4);
            af[kk] = *(const bfx8*)((char*)hlds + boff);
        }
    }

    float pd[4] = {0.f, 0.f, 0.f, 0.f};
#pragma unroll
    for (int cf = 0; cf < 8; ++cf) {
        fx4 acc = {0.f, 0.f, 0.f, 0.f};
        const unsigned short* wp = Mw1 + (size_t)(cf * 16 + r) * HD + ko;
#pragma unroll
        for (int kk = 0; kk < 4; ++kk) {
            bfx8 w = *(const bfx8*)(wp + kk * 32);
            acc = __builtin_amdgcn_mfma_f32_16x16x32_bf16(af[kk], w, acc, 0, 0, 0);
        }
        float bv = mb1[cf * 16 + r];
        float m  = mw2[cf * 16 + r];
#pragma unroll
        for (int j = 0; j < 4; ++j)
            pd[j] += fmaxf(acc[j] + bv, 0.f) * m;
    }

#pragma unroll
    for (int s = 1; s < 16; s <<= 1) {
#pragma unroll
        for (int j = 0; j < 4; ++j)
            pd[j] += __shfl_xor(pd[j], s, 64);
    }
    if (r == 0) {
        float mb = mb2[0];
#pragma unroll
        for (int j = 0; j < 4; ++j) {
            int row = row0 + hi * 4 + j;
            if (row < nrows) outf[row] = pd[j] + mb;
        }
    }
}

// ---------------- launch ----------------

extern "C" void kernel_launch(void* const* d_in, const int* in_sizes, int n_in,
                              void* d_out, int out_size, void* d_ws, size_t ws_size,
                              hipStream_t stream) {
    const float* x   = (const float*)d_in[0];
    const int*   ei  = (const int*)d_in[1];   // [2,E] int32
    const float* w1l = (const float*)d_in[2];
    const float* b1l = (const float*)d_in[3];
    const float* w1r = (const float*)d_in[4];
    const float* w2l = (const float*)d_in[5];
    const float* b2l = (const float*)d_in[6];
    const float* w2r = (const float*)d_in[7];
    const float* mw1 = (const float*)d_in[8];
    const float* mb1 = (const float*)d_in[9];
    const float* mw2 = (const float*)d_in[10];
    const float* mb2 = (const float*)d_in[11];
    float* out = (float*)d_out;

    const int N = in_sizes[0] / HD;   // 50000
    const int E = in_sizes[1] / 2;    // 1600000
    const int NBK = (N + 63) / 64;    // 782

    char* p = (char*)d_ws;
    auto alloc = [&](size_t bytes) -> char* {
        char* q = p;
        p += (bytes + 255) & ~(size_t)255;
        return q;
    };
    int*            bcnt    = (int*)alloc((size_t)NBK * 4);
    int*            boff    = (int*)alloc(((size_t)NBK + 1) * 4);
    int*            offsets = (int*)alloc(((size_t)N + 1) * 4);
    int*            bsrc    = (int*)alloc((size_t)NBK * CAP * 4);
    int*            bdst    = (int*)alloc((size_t)NBK * CAP * 4);
    int*            sorted  = (int*)alloc((size_t)E * 4);
    unsigned short* Wtb     = (unsigned short*)alloc((size_t)5 * HD * HD * 2);
    unsigned short* xb      = (unsigned short*)alloc((size_t)N * HD * 2);
    unsigned short* bufA    = (unsigned short*)alloc((size_t)N * HD * 2);
    unsigned short* bufB    = (unsigned short*)alloc((size_t)N * HD * 2);

    const unsigned short* W1l = Wtb + 0 * HD * HD;
    const unsigned short* W1r = Wtb + 1 * HD * HD;
    const unsigned short* W2l = Wtb + 2 * HD * HD;
    const unsigned short* W2r = Wtb + 3 * HD * HD;
    const unsigned short* Mw1 = Wtb + 4 * HD * HD;

    const int eb4k = (E + 4095) / 4096;    // 391
    const int gb   = (N + 63) / 64;        // 782
    const int ab   = (N + 3) / 4;          // 12500

    // CSR build (bucketed, low-atomic)
    k_zero<<<(NBK + 255) / 256, 256, 0, stream>>>(bcnt, NBK);
    k_bin<<<eb4k, 256, 0, stream>>>(ei, E, NBK, bcnt, bsrc, bdst);
    k_bscan<<<1, 1024, 0, stream>>>(bcnt, boff, NBK, E);
    k_bucket<<<NBK, 256, 0, stream>>>(bsrc, bdst, bcnt, boff, offsets, sorted, N, E);

    // casts
    k_cast<<<(N * HD / 8 + 255) / 256, 256, 0, stream>>>(x, xb, N * HD / 8);
    k_cast5<<<40, 256, 0, stream>>>(w1l, w1r, w2l, w2r, mw1, Wtb);

    // layer 1
    k_aggr<<<ab, 256, 0, stream>>>(xb, offsets, sorted, bufA, N);
    k_gemm_mfma<<<gb, 256, 0, stream>>>(bufA, xb, W1l, W1r, b1l, bufB, N);
    // layer 2 aggr
    k_aggr<<<ab, 256, 0, stream>>>(bufB, offsets, sorted, bufA, N);
    // layer 2 GEMM + MLP + final, fused
    k_l2_fused<<<gb, 256, 0, stream>>>(bufA, bufB, W2l, W2r, b2l, Mw1, mb1, mw2, mb2,
                                       out, N);
}

// Round 7
// 320.678 us; speedup vs baseline: 2.3241x; 1.0421x over previous
//
#include <hip/hip_runtime.h>
#include <hip/hip_bf16.h>
#include <cstdint>

#define HD 128
#define BKSZ 256          // nodes per bucket
#define BCAP 12288        // bucket capacity (mean fill 8163, ~45 sigma headroom)

typedef __attribute__((ext_vector_type(8))) short bfx8;   // 8 bf16 in 4 VGPRs
typedef __attribute__((ext_vector_type(4))) float fx4;

__device__ inline float bf2f(short s) {
    union { uint32_t u; float f; } c;
    c.u = ((uint32_t)(unsigned short)s) << 16;
    return c.f;
}
__device__ inline unsigned short f2bf(float v) {
    union { float f; uint32_t u; } c;
    c.f = v;
    uint32_t u = c.u + 0x7FFF + ((c.u >> 16) & 1);   // RNE
    return (unsigned short)(u >> 16);
}

// ---------------- bucketed CSR build ----------------
// bucket b = dst >> 8 (256 nodes/bucket, NBK = 196). Edge packed into one word:
// (dst & 255) << 24 | src   (requires src < 2^24 — N = 50000).

__global__ void k_zero(int* __restrict__ p, int n) {
    int i = blockIdx.x * 256 + threadIdx.x;
    if (i < n) p[i] = 0;
}

// Phase 1: LDS-aggregated binning; one packed 4B write per edge; ~21-edge runs
// per (block,bucket) -> ~1.5x line amplification instead of 6.6x.
__global__ __launch_bounds__(256) void k_bin(const int* __restrict__ ei, int E, int NBK,
                                             int* __restrict__ bcnt,
                                             int* __restrict__ bpack) {
    __shared__ int lhist[BKSZ];
    __shared__ int gbase[BKSZ];
    int base = blockIdx.x * 4096;

    for (int i = threadIdx.x; i < NBK; i += 256) lhist[i] = 0;
    __syncthreads();

    int pw[16];
    int meta[16];
    const int4* s4 = (const int4*)ei;
    const int4* d4 = (const int4*)(ei + E);
    int c0 = base >> 2;
    int EC = E >> 2;                       // E % 4 == 0
#pragma unroll
    for (int j = 0; j < 4; ++j) {
        int c4 = c0 + j * 256 + threadIdx.x;
        bool ok = (c4 < EC);
        int4 sv = make_int4(0, 0, 0, 0), dv = make_int4(0, 0, 0, 0);
        if (ok) { sv = s4[c4]; dv = d4[c4]; }
        int ss[4] = {sv.x, sv.y, sv.z, sv.w};
        int dd[4] = {dv.x, dv.y, dv.z, dv.w};
#pragma unroll
        for (int l = 0; l < 4; ++l) {
            int idx = j * 4 + l;
            meta[idx] = -1;
            if (ok) {
                int d = dd[l];
                int b = d >> 8;
                int lr = atomicAdd(&lhist[b], 1);          // LDS atomic
                pw[idx]   = ((d & 255) << 24) | ss[l];
                meta[idx] = (b << 16) | lr;                // b<=195, lr<4096
            }
        }
    }
    __syncthreads();
    for (int i = threadIdx.x; i < NBK; i += 256) {
        int c = lhist[i];
        gbase[i] = c ? atomicAdd(&bcnt[i], c) : 0;         // 1 global atomic/bucket
    }
    __syncthreads();
#pragma unroll
    for (int idx = 0; idx < 16; ++idx) {
        int m = meta[idx];
        if (m >= 0) {
            int b = m >> 16, lr = m & 0xFFFF;
            int pos = b * BCAP + min(gbase[b] + lr, BCAP - 1);  // clamp: no OOB
            bpack[pos] = pw[idx];
        }
    }
}

// Phase 2: exclusive scan of bucket counts (NBK <= 1024, one block)
__global__ __launch_bounds__(1024) void k_bscan(const int* __restrict__ bcnt,
                                                int* __restrict__ boff, int NBK, int E) {
    __shared__ int sh[1024];
    int t = threadIdx.x;
    int v = (t < NBK) ? bcnt[t] : 0;
    sh[t] = v;
    __syncthreads();
    for (int d = 1; d < 1024; d <<= 1) {
        int o = (t >= d) ? sh[t - d] : 0;
        __syncthreads();
        sh[t] += o;
        __syncthreads();
    }
    if (t < NBK) boff[t] = sh[t] - v;     // exclusive
    if (t == 0) boff[NBK] = E;
}

// Phase 3: per-bucket local sort (256 LDS counters). Output region is
// block-owned and contiguous -> full-line writes, no cross-XCD sharing.
__global__ __launch_bounds__(256) void k_bucket(const int* __restrict__ bpack,
                                                const int* __restrict__ bcnt,
                                                const int* __restrict__ boff,
                                                int* __restrict__ offsets,
                                                int* __restrict__ sorted,
                                                int N, int E) {
    __shared__ int lh[BKSZ];
    __shared__ int cur[BKSZ];
    __shared__ int wsum[4];
    int b = blockIdx.x;
    int cnt = min(bcnt[b], BCAP);
    int base = b * BCAP;
    int obase = boff[b];
    int tid = threadIdx.x;

    lh[tid] = 0;
    __syncthreads();
    for (int i = tid; i < cnt; i += 256)
        atomicAdd(&lh[((unsigned)bpack[base + i]) >> 24], 1);
    __syncthreads();

    // 256-entry exclusive scan: intra-wave shfl + cross-wave prefix
    int v = lh[tid];
    int sum = v;
#pragma unroll
    for (int s = 1; s < 64; s <<= 1) {
        int o = __shfl_up(sum, s, 64);
        if ((tid & 63) >= s) sum += o;
    }
    int wid = tid >> 6;
    if ((tid & 63) == 63) wsum[wid] = sum;
    __syncthreads();
    int prefix = 0;
#pragma unroll
    for (int w = 0; w < 4; ++w)
        if (w < wid) prefix += wsum[w];
    int excl = prefix + sum - v;
    int n = b * BKSZ + tid;
    if (n < N) offsets[n] = obase + excl;
    cur[tid] = excl;
    __syncthreads();

    for (int i = tid; i < cnt; i += 256) {
        int w = bpack[base + i];
        int ln = ((unsigned)w) >> 24;
        int p = atomicAdd(&cur[ln], 1);          // LDS atomic
        sorted[obase + p] = w & 0xFFFFFF;
    }
    if (b == 0 && tid == 0) offsets[N] = E;
}

// ---------------- fp32 -> bf16 casts ----------------

__global__ void k_cast(const float* __restrict__ in, unsigned short* __restrict__ out,
                       int n8) {
    int i = blockIdx.x * 256 + threadIdx.x;
    if (i >= n8) return;
    float4 v0 = ((const float4*)in)[i * 2];
    float4 v1 = ((const float4*)in)[i * 2 + 1];
    bfx8 o;
    o[0] = (short)f2bf(v0.x); o[1] = (short)f2bf(v0.y);
    o[2] = (short)f2bf(v0.z); o[3] = (short)f2bf(v0.w);
    o[4] = (short)f2bf(v1.x); o[5] = (short)f2bf(v1.y);
    o[6] = (short)f2bf(v1.z); o[7] = (short)f2bf(v1.w);
    *(bfx8*)(out + (size_t)i * 8) = o;
}

__global__ void k_cast5(const float* __restrict__ w0, const float* __restrict__ w1,
                        const float* __restrict__ w2, const float* __restrict__ w3,
                        const float* __restrict__ w4, unsigned short* __restrict__ out) {
    int t = blockIdx.x * 256 + threadIdx.x;   // 10240 threads, 8 elems each
    if (t >= 5 * 2048) return;
    int w = t / 2048, j = t % 2048;
    const float* src = (w == 0) ? w0 : (w == 1) ? w1 : (w == 2) ? w2 : (w == 3) ? w3 : w4;
    float4 v0 = ((const float4*)src)[j * 2];
    float4 v1 = ((const float4*)src)[j * 2 + 1];
    bfx8 o;
    o[0] = (short)f2bf(v0.x); o[1] = (short)f2bf(v0.y);
    o[2] = (short)f2bf(v0.z); o[3] = (short)f2bf(v0.w);
    o[4] = (short)f2bf(v1.x); o[5] = (short)f2bf(v1.y);
    o[6] = (short)f2bf(v1.z); o[7] = (short)f2bf(v1.w);
    *(bfx8*)(out + (size_t)t * 8) = o;
}

// ---------------- mean aggregation: one wave per node, shfl reduce ----------------

__global__ __launch_bounds__(256) void k_aggr(const unsigned short* __restrict__ x,
                                              const int* __restrict__ offsets,
                                              const int* __restrict__ sorted_src,
                                              unsigned short* __restrict__ out, int N) {
    int wid  = threadIdx.x >> 6;
    int lane = threadIdx.x & 63;
    int n = blockIdx.x * 4 + wid;
    if (n >= N) return;
    int slot = lane >> 4;     // 0..3
    int c    = lane & 15;     // feature octet
    int beg = offsets[n], end = offsets[n + 1];

    float acc[8];
#pragma unroll
    for (int j = 0; j < 8; ++j) acc[j] = 0.f;

    int e = beg + slot;
    for (; e + 4 < end; e += 8) {
        int i0 = sorted_src[e];
        int i1 = sorted_src[e + 4];
        bfx8 v0 = *(const bfx8*)(x + (size_t)i0 * HD + c * 8);
        bfx8 v1 = *(const bfx8*)(x + (size_t)i1 * HD + c * 8);
#pragma unroll
        for (int j = 0; j < 8; ++j) acc[j] += bf2f(v0[j]);
#pragma unroll
        for (int j = 0; j < 8; ++j) acc[j] += bf2f(v1[j]);
    }
    if (e < end) {
        int i0 = sorted_src[e];
        bfx8 v0 = *(const bfx8*)(x + (size_t)i0 * HD + c * 8);
#pragma unroll
        for (int j = 0; j < 8; ++j) acc[j] += bf2f(v0[j]);
    }

#pragma unroll
    for (int j = 0; j < 8; ++j) {
        acc[j] += __shfl_xor(acc[j], 16, 64);
        acc[j] += __shfl_xor(acc[j], 32, 64);
    }
    if (slot == 0) {
        float inv = 1.f / fmaxf((float)(end - beg), 1.f);
        bfx8 o;
#pragma unroll
        for (int j = 0; j < 8; ++j) o[j] = (short)f2bf(acc[j] * inv);
        *(bfx8*)(out + (size_t)n * HD + c * 8) = o;
    }
}

// ---------------- layer-1 MFMA dual GEMM ----------------
// mfma_f32_16x16x32_bf16: A lane: row=l&15, k=(l>>4)*8+j ; B lane: col=l&15 ;
// D: col=l&15, row=(l>>4)*4+reg  [m89-verified]. W native [out][k] = B frag directly.

__global__ __launch_bounds__(256) void k_gemm_mfma(
    const unsigned short* __restrict__ A,
    const unsigned short* __restrict__ B,
    const unsigned short* __restrict__ Wl,
    const unsigned short* __restrict__ Wr,
    const float* __restrict__ bias,
    unsigned short* __restrict__ outb, int nrows) {
    int wid  = threadIdx.x >> 6;
    int lane = threadIdx.x & 63;
    int r  = lane & 15;
    int hi = lane >> 4;          // 0..3
    int ko = hi * 8;
    int row0 = blockIdx.x * 64 + wid * 16;

    int arow  = row0 + r;
    int arowc = min(arow, nrows - 1);

    bfx8 a[4], b[4];
    const unsigned short* Ar = A + (size_t)arowc * HD;
    const unsigned short* Br = B + (size_t)arowc * HD;
#pragma unroll
    for (int kk = 0; kk < 4; ++kk) {
        a[kk] = *(const bfx8*)(Ar + kk * 32 + ko);
        b[kk] = *(const bfx8*)(Br + kk * 32 + ko);
    }

#pragma unroll
    for (int cf = 0; cf < 8; ++cf) {
        fx4 acc = {0.f, 0.f, 0.f, 0.f};
        const unsigned short* wlp = Wl + (size_t)(cf * 16 + r) * HD + ko;
        const unsigned short* wrp = Wr + (size_t)(cf * 16 + r) * HD + ko;
#pragma unroll
        for (int kk = 0; kk < 4; ++kk) {
            bfx8 wl = *(const bfx8*)(wlp + kk * 32);
            acc = __builtin_amdgcn_mfma_f32_16x16x32_bf16(a[kk], wl, acc, 0, 0, 0);
        }
#pragma unroll
        for (int kk = 0; kk < 4; ++kk) {
            bfx8 wr = *(const bfx8*)(wrp + kk * 32);
            acc = __builtin_amdgcn_mfma_f32_16x16x32_bf16(b[kk], wr, acc, 0, 0, 0);
        }
        float bv = bias[cf * 16 + r];
#pragma unroll
        for (int j = 0; j < 4; ++j) {
            int row = row0 + hi * 4 + j;
            if (row < nrows)
                outb[(size_t)row * HD + cf * 16 + r] = f2bf(fmaxf(acc[j] + bv, 0.f));
        }
    }
}

// ---------------- fused layer2 + MLP + final dot ----------------
// LDS swizzle: byte ^= (row&7)<<4 spreads stage-2 b128 column reads over banks.

__global__ __launch_bounds__(256) void k_l2_fused(
    const unsigned short* __restrict__ A,     // aggr2
    const unsigned short* __restrict__ B,     // h1
    const unsigned short* __restrict__ Wl,    // w2l
    const unsigned short* __restrict__ Wr,    // w2r
    const float* __restrict__ bias,           // b2l
    const unsigned short* __restrict__ Mw1,   // mw1 bf16
    const float* __restrict__ mb1,
    const float* __restrict__ mw2,
    const float* __restrict__ mb2,
    float* __restrict__ outf, int nrows) {
    __shared__ unsigned short hlds[64 * HD];   // 16 KB

    int wid  = threadIdx.x >> 6;
    int lane = threadIdx.x & 63;
    int r  = lane & 15;
    int hi = lane >> 4;
    int ko = hi * 8;
    int row0 = blockIdx.x * 64 + wid * 16;

    int arow  = row0 + r;
    int arowc = min(arow, nrows - 1);

    bfx8 a[4], b[4];
    const unsigned short* Ar = A + (size_t)arowc * HD;
    const unsigned short* Br = B + (size_t)arowc * HD;
#pragma unroll
    for (int kk = 0; kk < 4; ++kk) {
        a[kk] = *(const bfx8*)(Ar + kk * 32 + ko);
        b[kk] = *(const bfx8*)(Br + kk * 32 + ko);
    }

    // ---- stage 1: h2 tile into LDS ----
#pragma unroll
    for (int cf = 0; cf < 8; ++cf) {
        fx4 acc = {0.f, 0.f, 0.f, 0.f};
        const unsigned short* wlp = Wl + (size_t)(cf * 16 + r) * HD + ko;
        const unsigned short* wrp = Wr + (size_t)(cf * 16 + r) * HD + ko;
#pragma unroll
        for (int kk = 0; kk < 4; ++kk) {
            bfx8 wl = *(const bfx8*)(wlp + kk * 32);
            acc = __builtin_amdgcn_mfma_f32_16x16x32_bf16(a[kk], wl, acc, 0, 0, 0);
        }
#pragma unroll
        for (int kk = 0; kk < 4; ++kk) {
            bfx8 wr = *(const bfx8*)(wrp + kk * 32);
            acc = __builtin_amdgcn_mfma_f32_16x16x32_bf16(b[kk], wr, acc, 0, 0, 0);
        }
        float bv = bias[cf * 16 + r];
#pragma unroll
        for (int j = 0; j < 4; ++j) {
            int row_l = wid * 16 + hi * 4 + j;        // 0..63 block-local
            unsigned boff = (unsigned)(row_l * 256 + (cf * 16 + r) * 2);
            boff ^= (unsigned)((row_l & 7) << 4);
            *(unsigned short*)((char*)hlds + boff) = f2bf(fmaxf(acc[j] + bv, 0.f));
        }
    }
    __syncthreads();

    // ---- stage 2: h2 A-frags from LDS, GEMM vs Mw1, fused mw2 dot ----
    bfx8 af[4];
    {
        int row_l = wid * 16 + r;
#pragma unroll
        for (int kk = 0; kk < 4; ++kk) {
            unsigned boff = (unsigned)(row_l * 256 + (kk * 32 + ko) * 2);
            boff ^= (unsigned)((row_l & 7) << 4);
            af[kk] = *(const bfx8*)((char*)hlds + boff);
        }
    }

    float pd[4] = {0.f, 0.f, 0.f, 0.f};
#pragma unroll
    for (int cf = 0; cf < 8; ++cf) {
        fx4 acc = {0.f, 0.f, 0.f, 0.f};
        const unsigned short* wp = Mw1 + (size_t)(cf * 16 + r) * HD + ko;
#pragma unroll
        for (int kk = 0; kk < 4; ++kk) {
            bfx8 w = *(const bfx8*)(wp + kk * 32);
            acc = __builtin_amdgcn_mfma_f32_16x16x32_bf16(af[kk], w, acc, 0, 0, 0);
        }
        float bv = mb1[cf * 16 + r];
        float m  = mw2[cf * 16 + r];
#pragma unroll
        for (int j = 0; j < 4; ++j)
            pd[j] += fmaxf(acc[j] + bv, 0.f) * m;
    }

#pragma unroll
    for (int s = 1; s < 16; s <<= 1) {
#pragma unroll
        for (int j = 0; j < 4; ++j)
            pd[j] += __shfl_xor(pd[j], s, 64);
    }
    if (r == 0) {
        float mb = mb2[0];
#pragma unroll
        for (int j = 0; j < 4; ++j) {
            int row = row0 + hi * 4 + j;
            if (row < nrows) outf[row] = pd[j] + mb;
        }
    }
}

// ---------------- launch ----------------

extern "C" void kernel_launch(void* const* d_in, const int* in_sizes, int n_in,
                              void* d_out, int out_size, void* d_ws, size_t ws_size,
                              hipStream_t stream) {
    const float* x   = (const float*)d_in[0];
    const int*   ei  = (const int*)d_in[1];   // [2,E] int32
    const float* w1l = (const float*)d_in[2];
    const float* b1l = (const float*)d_in[3];
    const float* w1r = (const float*)d_in[4];
    const float* w2l = (const float*)d_in[5];
    const float* b2l = (const float*)d_in[6];
    const float* w2r = (const float*)d_in[7];
    const float* mw1 = (const float*)d_in[8];
    const float* mb1 = (const float*)d_in[9];
    const float* mw2 = (const float*)d_in[10];
    const float* mb2 = (const float*)d_in[11];
    float* out = (float*)d_out;

    const int N = in_sizes[0] / HD;   // 50000
    const int E = in_sizes[1] / 2;    // 1600000
    const int NBK = (N + BKSZ - 1) / BKSZ;   // 196

    char* p = (char*)d_ws;
    auto alloc = [&](size_t bytes) -> char* {
        char* q = p;
        p += (bytes + 255) & ~(size_t)255;
        return q;
    };
    int*            bcnt    = (int*)alloc((size_t)NBK * 4);
    int*            boff    = (int*)alloc(((size_t)NBK + 1) * 4);
    int*            offsets = (int*)alloc(((size_t)N + 1) * 4);
    int*            bpack   = (int*)alloc((size_t)NBK * BCAP * 4);
    int*            sorted  = (int*)alloc((size_t)E * 4);
    unsigned short* Wtb     = (unsigned short*)alloc((size_t)5 * HD * HD * 2);
    unsigned short* xb      = (unsigned short*)alloc((size_t)N * HD * 2);
    unsigned short* bufA    = (unsigned short*)alloc((size_t)N * HD * 2);
    unsigned short* bufB    = (unsigned short*)alloc((size_t)N * HD * 2);

    const unsigned short* W1l = Wtb + 0 * HD * HD;
    const unsigned short* W1r = Wtb + 1 * HD * HD;
    const unsigned short* W2l = Wtb + 2 * HD * HD;
    const unsigned short* W2r = Wtb + 3 * HD * HD;
    const unsigned short* Mw1 = Wtb + 4 * HD * HD;

    const int eb4k = (E + 4095) / 4096;    // 391
    const int gb   = (N + 63) / 64;        // 782
    const int ab   = (N + 3) / 4;          // 12500

    // CSR build (bucketed, packed, low-atomic)
    k_zero<<<1, 256, 0, stream>>>(bcnt, NBK);
    k_bin<<<eb4k, 256, 0, stream>>>(ei, E, NBK, bcnt, bpack);
    k_bscan<<<1, 1024, 0, stream>>>(bcnt, boff, NBK, E);
    k_bucket<<<NBK, 256, 0, stream>>>(bpack, bcnt, boff, offsets, sorted, N, E);

    // casts
    k_cast<<<(N * HD / 8 + 255) / 256, 256, 0, stream>>>(x, xb, N * HD / 8);
    k_cast5<<<40, 256, 0, stream>>>(w1l, w1r, w2l, w2r, mw1, Wtb);

    // layer 1
    k_aggr<<<ab, 256, 0, stream>>>(xb, offsets, sorted, bufA, N);
    k_gemm_mfma<<<gb, 256, 0, stream>>>(bufA, xb, W1l, W1r, b1l, bufB, N);
    // layer 2 aggr
    k_aggr<<<ab, 256, 0, stream>>>(bufB, offsets, sorted, bufA, N);
    // layer 2 GEMM + MLP + final, fused
    k_l2_fused<<<gb, 256, 0, stream>>>(bufA, bufB, W2l, W2r, b2l, Mw1, mb1, mw2, mb2,
                                       out, N);
}